// Round 1
// baseline (305.590 us; speedup 1.0000x reference)
//
#include <hip/hip_runtime.h>

#define S_LEN 2048
#define NHEADS 14
#define NKVH 2
#define HDIM 64
#define HID 896
#define NQKV 1152

typedef __bf16 bf16;
typedef __bf16 bf16x4 __attribute__((ext_vector_type(4)));
typedef __bf16 bf16x8 __attribute__((ext_vector_type(8)));
typedef float f32x4 __attribute__((ext_vector_type(4)));

__device__ inline f32x4 mfma16(bf16x8 a, bf16x8 b, f32x4 c) {
  return __builtin_amdgcn_mfma_f32_16x16x32_bf16(a, b, c, 0, 0, 0);
}

__device__ inline void gload_lds16(const bf16* g, bf16* l) {
  __builtin_amdgcn_global_load_lds(
      (const __attribute__((address_space(1))) void*)g,
      (__attribute__((address_space(3))) void*)l, 16, 0, 0);
}

// ---------------- cast / pack kernels ----------------
__global__ __launch_bounds__(256) void cast_x_kernel(const float* __restrict__ X,
                                                     bf16* __restrict__ Xb, int n4) {
  int i = blockIdx.x * 256 + threadIdx.x;
  if (i >= n4) return;
  float4 v = reinterpret_cast<const float4*>(X)[i];
  bf16x4 o;
  o[0] = (bf16)v.x; o[1] = (bf16)v.y; o[2] = (bf16)v.z; o[3] = (bf16)v.w;
  reinterpret_cast<bf16x4*>(Xb)[i] = o;
}

// W: [896][N] f32 row-major  ->  WT: [N][896] bf16 row-major
__global__ __launch_bounds__(256) void transpose_cast_kernel(const float* __restrict__ W,
                                                             bf16* __restrict__ WT, int N) {
  __shared__ float tile[32][33];
  int n0 = blockIdx.x * 32, k0 = blockIdx.y * 32;
  int tx = threadIdx.x & 31, ty = threadIdx.x >> 5;  // 32 x 8
#pragma unroll
  for (int j = 0; j < 32; j += 8)
    tile[ty + j][tx] = W[(size_t)(k0 + ty + j) * N + n0 + tx];
  __syncthreads();
#pragma unroll
  for (int j = 0; j < 32; j += 8)
    WT[(size_t)(n0 + ty + j) * HID + k0 + tx] = (bf16)tile[tx][ty + j];
}

__global__ __launch_bounds__(256) void pack_bias_kernel(const float* __restrict__ bq,
                                                        const float* __restrict__ bk,
                                                        const float* __restrict__ bv,
                                                        float* __restrict__ out) {
  int i = blockIdx.x * 256 + threadIdx.x;
  if (i < 896) out[i] = bq[i];
  else if (i < 1024) out[i] = bk[i - 896];
  else if (i < 1152) out[i] = bv[i - 1024];
}

// ---------------- GEMM: C[M][N] = A[M][K](bf16) * Bt[N][K](bf16)^T + bias ----------------
__global__ __launch_bounds__(256) void gemm_bt_kernel(const bf16* __restrict__ A,
                                                      const bf16* __restrict__ Bt,
                                                      const float* __restrict__ bias,
                                                      float* __restrict__ C,
                                                      int M, int N, int K) {
  __shared__ __align__(16) bf16 As[2][128][32];
  __shared__ __align__(16) bf16 Bs[2][128][32];
  int n0 = blockIdx.x * 128, m0 = blockIdx.y * 128;
  int tid = threadIdx.x;
  int wid = tid >> 6, lane = tid & 63;
  int lr = lane & 15, lh = lane >> 4;
  int wr = wid >> 1, wc = wid & 1;
  f32x4 acc[4][4] = {};

  auto stage = [&](int buf, int k0) {
#pragma unroll
    for (int i = 0; i < 2; ++i) {
      int seg = i * 4 + wid;              // 0..7, wave-uniform
      int idx = seg * 512 + lane * 8;     // element index within 128x32 tile
      int r = idx >> 5, c = idx & 31;
      gload_lds16(A + (size_t)(m0 + r) * K + k0 + c, &As[buf][0][0] + seg * 512);
      gload_lds16(Bt + (size_t)(n0 + r) * K + k0 + c, &Bs[buf][0][0] + seg * 512);
    }
  };

  stage(0, 0);
  __syncthreads();
  int nk = K >> 5;
  int cur = 0;
  for (int t = 0; t < nk; ++t) {
    if (t + 1 < nk) stage(cur ^ 1, (t + 1) << 5);
    bf16x8 am[4], bn[4];
#pragma unroll
    for (int mf = 0; mf < 4; ++mf)
      am[mf] = *reinterpret_cast<const bf16x8*>(&As[cur][wr * 64 + mf * 16 + lr][lh * 8]);
#pragma unroll
    for (int nf = 0; nf < 4; ++nf)
      bn[nf] = *reinterpret_cast<const bf16x8*>(&Bs[cur][wc * 64 + nf * 16 + lr][lh * 8]);
#pragma unroll
    for (int mf = 0; mf < 4; ++mf)
#pragma unroll
      for (int nf = 0; nf < 4; ++nf)
        acc[mf][nf] = mfma16(am[mf], bn[nf], acc[mf][nf]);
    __syncthreads();   // drains vmcnt (staged loads) + lgkm before buffer flip
    cur ^= 1;
  }

#pragma unroll
  for (int nf = 0; nf < 4; ++nf) {
    int col = n0 + wc * 64 + nf * 16 + lr;
    float b = bias ? bias[col] : 0.f;
#pragma unroll
    for (int mf = 0; mf < 4; ++mf) {
      int row0 = m0 + wr * 64 + mf * 16 + lh * 4;
#pragma unroll
      for (int j = 0; j < 4; ++j)
        C[(size_t)(row0 + j) * N + col] = acc[mf][nf][j] + b;
    }
  }
}

// ---------------- RoPE + layout ----------------
// QKV: [4096][1152] f32. Writes Qb [B][14][S][64] (pre-scaled 1/8), Kb [B][2][S][64], Vt [B][2][64][S]
__global__ __launch_bounds__(256) void rope_kernel(const float* __restrict__ QKV,
                                                   bf16* __restrict__ Qb,
                                                   bf16* __restrict__ Kb,
                                                   bf16* __restrict__ Vt) {
  int t = blockIdx.x;
  int b = t >> 11, s = t & (S_LEN - 1);
  const float* row = QKV + (size_t)t * NQKV;
  int tid = threadIdx.x;
  __shared__ float cs[32], sn[32];
  if (tid < 32) {
    float inv = expf(-(float)tid * (13.815510557964274f / 32.0f));  // 1e6^(-d/32)
    float a = (float)s * inv;
    float c, si;
    sincosf(a, &si, &c);
    cs[tid] = c; sn[tid] = si;
  }
  __syncthreads();
  // Q: 14 heads x 32 pairs
  for (int p = tid; p < NHEADS * 32; p += 256) {
    int h = p >> 5, d = p & 31;
    float v1 = row[h * 64 + d], v2 = row[h * 64 + d + 32];
    float c = cs[d], si = sn[d];
    size_t base = ((size_t)(b * NHEADS + h) * S_LEN + s) * HDIM;
    Qb[base + d]      = (bf16)((v1 * c - v2 * si) * 0.125f);
    Qb[base + d + 32] = (bf16)((v2 * c + v1 * si) * 0.125f);
  }
  // K: 2 heads x 32 pairs
  if (tid < NKVH * 32) {
    int kh = tid >> 5, d = tid & 31;
    float v1 = row[896 + kh * 64 + d], v2 = row[896 + kh * 64 + d + 32];
    float c = cs[d], si = sn[d];
    size_t base = ((size_t)(b * NKVH + kh) * S_LEN + s) * HDIM;
    Kb[base + d]      = (bf16)(v1 * c - v2 * si);
    Kb[base + d + 32] = (bf16)(v2 * c + v1 * si);
  }
  // V transposed
  if (tid < NKVH * 64) {
    int kh = tid >> 6, d = tid & 63;
    float v = row[1024 + tid];
    Vt[((size_t)(b * NKVH + kh) * HDIM + d) * S_LEN + s] = (bf16)v;
  }
}

// ---------------- flash attention (causal, GQA) ----------------
__global__ __launch_bounds__(256) void attn_kernel(const bf16* __restrict__ Qb,
                                                   const bf16* __restrict__ Kb,
                                                   const bf16* __restrict__ Vt,
                                                   bf16* __restrict__ Ob) {
  int blk = blockIdx.x;
  int qt = blk & 31, bh = blk >> 5;
  int h = bh % NHEADS, b = bh / NHEADS;
  int q0 = qt * 64;
  int kv = h / 7;
  int tid = threadIdx.x, wid = tid >> 6, lane = tid & 63;
  int lr = lane & 15, lh = lane >> 4;

  const bf16* Qp = Qb + ((size_t)(b * NHEADS + h) * S_LEN + q0 + wid * 16) * HDIM;
  const bf16* Kp = Kb + ((size_t)(b * NKVH + kv) * S_LEN) * HDIM;
  const bf16* Vp = Vt + ((size_t)(b * NKVH + kv) * HDIM) * S_LEN;

  bf16x8 aq[2];
#pragma unroll
  for (int kk = 0; kk < 2; ++kk)
    aq[kk] = *reinterpret_cast<const bf16x8*>(Qp + (size_t)lr * HDIM + kk * 32 + lh * 8);

  float m[4], l[4];
  f32x4 o[4] = {};
#pragma unroll
  for (int j = 0; j < 4; ++j) { m[j] = -__builtin_inff(); l[j] = 0.f; }

  __shared__ __align__(16) bf16 Plds[4][16][72];

  int rowg = q0 + wid * 16 + lh * 4;  // + j gives the global query row
  for (int kv0 = 0; kv0 <= q0; kv0 += 64) {
    bool diag = (kv0 == q0);
    f32x4 sacc[4] = {};
#pragma unroll
    for (int nf = 0; nf < 4; ++nf) {
#pragma unroll
      for (int kk = 0; kk < 2; ++kk) {
        bf16x8 bk = *reinterpret_cast<const bf16x8*>(
            Kp + (size_t)(kv0 + nf * 16 + lr) * HDIM + kk * 32 + lh * 8);
        sacc[nf] = mfma16(aq[kk], bk, sacc[nf]);
      }
    }
    // online softmax
    float p[4][4], mloc[4];
#pragma unroll
    for (int j = 0; j < 4; ++j) mloc[j] = -__builtin_inff();
#pragma unroll
    for (int nf = 0; nf < 4; ++nf) {
      int colg = kv0 + nf * 16 + lr;
#pragma unroll
      for (int j = 0; j < 4; ++j) {
        float x = sacc[nf][j];
        if (diag && colg > rowg + j) x = -__builtin_inff();
        p[nf][j] = x;
        mloc[j] = fmaxf(mloc[j], x);
      }
    }
#pragma unroll
    for (int mask = 1; mask < 16; mask <<= 1)
#pragma unroll
      for (int j = 0; j < 4; ++j)
        mloc[j] = fmaxf(mloc[j], __shfl_xor(mloc[j], mask));
    float alpha[4], rs[4];
#pragma unroll
    for (int j = 0; j < 4; ++j) {
      float mn = fmaxf(m[j], mloc[j]);
      alpha[j] = __expf(m[j] - mn);
      m[j] = mn;
      rs[j] = 0.f;
    }
#pragma unroll
    for (int nf = 0; nf < 4; ++nf)
#pragma unroll
      for (int j = 0; j < 4; ++j) {
        float e = __expf(p[nf][j] - m[j]);
        p[nf][j] = e;
        rs[j] += e;
      }
#pragma unroll
    for (int mask = 1; mask < 16; mask <<= 1)
#pragma unroll
      for (int j = 0; j < 4; ++j)
        rs[j] += __shfl_xor(rs[j], mask);
#pragma unroll
    for (int j = 0; j < 4; ++j)
      l[j] = l[j] * alpha[j] + rs[j];
#pragma unroll
    for (int nf = 0; nf < 4; ++nf)
#pragma unroll
      for (int j = 0; j < 4; ++j)
        o[nf][j] *= alpha[j];
    // P -> LDS (per-wave private region, no barrier needed)
#pragma unroll
    for (int nf = 0; nf < 4; ++nf)
#pragma unroll
      for (int j = 0; j < 4; ++j)
        Plds[wid][lh * 4 + j][nf * 16 + lr] = (bf16)p[nf][j];
    bf16x8 pa[2];
#pragma unroll
    for (int kk = 0; kk < 2; ++kk)
      pa[kk] = *reinterpret_cast<const bf16x8*>(&Plds[wid][lr][kk * 32 + lh * 8]);
#pragma unroll
    for (int nf = 0; nf < 4; ++nf) {
#pragma unroll
      for (int kk = 0; kk < 2; ++kk) {
        bf16x8 bv = *reinterpret_cast<const bf16x8*>(
            Vp + (size_t)(nf * 16 + lr) * S_LEN + kv0 + kk * 32 + lh * 8);
        o[nf] = mfma16(pa[kk], bv, o[nf]);
      }
    }
  }
  // epilogue: O / l -> Ob [4096][896] bf16
#pragma unroll
  for (int nf = 0; nf < 4; ++nf) {
    int col = h * 64 + nf * 16 + lr;
#pragma unroll
    for (int j = 0; j < 4; ++j) {
      float ov = o[nf][j] / l[j];
      Ob[(size_t)((b * S_LEN) + q0 + wid * 16 + lh * 4 + j) * HID + col] = (bf16)ov;
    }
  }
}

// ---------------- launch ----------------
extern "C" void kernel_launch(void* const* d_in, const int* in_sizes, int n_in,
                              void* d_out, int out_size, void* d_ws, size_t ws_size,
                              hipStream_t stream) {
  (void)in_sizes; (void)n_in; (void)out_size; (void)ws_size;
  const float* X  = (const float*)d_in[0];
  // d_in[1] = attention_mask: causal, computed analytically -> never read
  const float* Wq = (const float*)d_in[2];
  const float* bq = (const float*)d_in[3];
  const float* Wk = (const float*)d_in[4];
  const float* bk = (const float*)d_in[5];
  const float* Wv = (const float*)d_in[6];
  const float* bv = (const float*)d_in[7];
  const float* Wo = (const float*)d_in[8];
  float* OUT = (float*)d_out;

  char* ws = (char*)d_ws;
  bf16*  Xb    = (bf16*)(ws);                 // 4096*896*2  = 7,340,032
  bf16*  WqkvT = (bf16*)(ws + 7340032);       // 1152*896*2  = 2,064,384
  bf16*  WoT   = (bf16*)(ws + 9404416);       // 896*896*2   = 1,605,632
  float* biasq = (float*)(ws + 11010048);     // 1152*4
  float* QKV   = (float*)(ws + 11014656);     // 4096*1152*4 = 18,874,368
  bf16*  Qbuf  = (bf16*)(ws + 29889024);      // 4096*896*2
  bf16*  Kbuf  = (bf16*)(ws + 37229056);      // 2*2*2048*64*2
  bf16*  Vbuf  = (bf16*)(ws + 38277632);      // 2*2*64*2048*2  (ends 39,326,208)
  bf16*  Obuf  = Xb;                          // reuse (Xb dead after GEMM1)

  cast_x_kernel<<<3584, 256, 0, stream>>>(X, Xb, 917504);
  transpose_cast_kernel<<<dim3(28, 28), 256, 0, stream>>>(Wq, WqkvT, 896);
  transpose_cast_kernel<<<dim3(4, 28), 256, 0, stream>>>(Wk, WqkvT + (size_t)896 * 896, 128);
  transpose_cast_kernel<<<dim3(4, 28), 256, 0, stream>>>(Wv, WqkvT + (size_t)1024 * 896, 128);
  transpose_cast_kernel<<<dim3(28, 28), 256, 0, stream>>>(Wo, WoT, 896);
  pack_bias_kernel<<<5, 256, 0, stream>>>(bq, bk, bv, biasq);

  gemm_bt_kernel<<<dim3(9, 32), 256, 0, stream>>>(Xb, WqkvT, biasq, QKV, 4096, 1152, 896);
  rope_kernel<<<4096, 256, 0, stream>>>(QKV, Qbuf, Kbuf, Vbuf);
  attn_kernel<<<896, 256, 0, stream>>>(Qbuf, Kbuf, Vbuf, Obuf);
  gemm_bt_kernel<<<dim3(7, 32), 256, 0, stream>>>(Obuf, WoT, nullptr, OUT, 4096, 896, 896);
}

// Round 2
// 231.255 us; speedup vs baseline: 1.3214x; 1.3214x over previous
//
#include <hip/hip_runtime.h>

#define S_LEN 2048
#define NHEADS 14
#define NKVH 2
#define HDIM 64
#define HID 896
#define NQKV 1152
#define NCHUNK 80   // sum over qt of ceil((qt+1)/8)

typedef __bf16 bf16;
typedef __bf16 bf16x4 __attribute__((ext_vector_type(4)));
typedef __bf16 bf16x8 __attribute__((ext_vector_type(8)));
typedef float f32x4 __attribute__((ext_vector_type(4)));

__device__ inline f32x4 mfma16(bf16x8 a, bf16x8 b, f32x4 c) {
  return __builtin_amdgcn_mfma_f32_16x16x32_bf16(a, b, c, 0, 0, 0);
}

__device__ inline void gload_lds16(const bf16* g, bf16* l) {
  __builtin_amdgcn_global_load_lds(
      (const __attribute__((address_space(1))) void*)g,
      (__attribute__((address_space(3))) void*)l, 16, 0, 0);
}

// chunk index c (0..79) -> (q-tile, chunk-within-tile)
__device__ inline void chunk_map(int c, int& qt, int& ch) {
  if (c < 8)       { qt = c;                 ch = 0; }
  else if (c < 24) { qt = 8 + ((c - 8) >> 1);  ch = (c - 8) & 1; }
  else if (c < 48) { int d = c - 24; qt = 16 + d / 3; ch = d % 3; }
  else             { int d = c - 48; qt = 24 + (d >> 2); ch = d & 3; }
}
__device__ inline int chunk_off(int qt) {
  if (qt < 8)  return qt;
  if (qt < 16) return 8 + 2 * (qt - 8);
  if (qt < 24) return 24 + 3 * (qt - 16);
  return 48 + 4 * (qt - 24);
}

// ---------------- cast / pack kernels ----------------
__global__ __launch_bounds__(256) void cast_x_kernel(const float* __restrict__ X,
                                                     bf16* __restrict__ Xb, int n4) {
  int i = blockIdx.x * 256 + threadIdx.x;
  if (i >= n4) return;
  float4 v = reinterpret_cast<const float4*>(X)[i];
  bf16x4 o;
  o[0] = (bf16)v.x; o[1] = (bf16)v.y; o[2] = (bf16)v.z; o[3] = (bf16)v.w;
  reinterpret_cast<bf16x4*>(Xb)[i] = o;
}

// W: [896][N] f32 row-major  ->  WT: [N][896] bf16 row-major
__global__ __launch_bounds__(256) void transpose_cast_kernel(const float* __restrict__ W,
                                                             bf16* __restrict__ WT, int N) {
  __shared__ float tile[32][33];
  int n0 = blockIdx.x * 32, k0 = blockIdx.y * 32;
  int tx = threadIdx.x & 31, ty = threadIdx.x >> 5;  // 32 x 8
#pragma unroll
  for (int j = 0; j < 32; j += 8)
    tile[ty + j][tx] = W[(size_t)(k0 + ty + j) * N + n0 + tx];
  __syncthreads();
#pragma unroll
  for (int j = 0; j < 32; j += 8)
    WT[(size_t)(n0 + ty + j) * HID + k0 + tx] = (bf16)tile[tx][ty + j];
}

__global__ __launch_bounds__(256) void pack_bias_kernel(const float* __restrict__ bq,
                                                        const float* __restrict__ bk,
                                                        const float* __restrict__ bv,
                                                        float* __restrict__ out) {
  int i = blockIdx.x * 256 + threadIdx.x;
  if (i < 896) out[i] = bq[i];
  else if (i < 1024) out[i] = bk[i - 896];
  else if (i < 1152) out[i] = bv[i - 1024];
}

// ---------------- GEMM: C[M][N] = A[M][K](bf16) * Bt[N][K](bf16)^T + bias ----------------
__global__ __launch_bounds__(256) void gemm_bt_kernel(const bf16* __restrict__ A,
                                                      const bf16* __restrict__ Bt,
                                                      const float* __restrict__ bias,
                                                      float* __restrict__ C,
                                                      int M, int N, int K) {
  __shared__ __align__(16) bf16 As[2][128][32];
  __shared__ __align__(16) bf16 Bs[2][128][32];
  int n0 = blockIdx.x * 128, m0 = blockIdx.y * 128;
  int tid = threadIdx.x;
  int wid = tid >> 6, lane = tid & 63;
  int lr = lane & 15, lh = lane >> 4;
  int wr = wid >> 1, wc = wid & 1;
  f32x4 acc[4][4] = {};

  auto stage = [&](int buf, int k0) {
#pragma unroll
    for (int i = 0; i < 2; ++i) {
      int seg = i * 4 + wid;              // 0..7, wave-uniform
      int idx = seg * 512 + lane * 8;     // element index within 128x32 tile
      int r = idx >> 5, c = idx & 31;
      gload_lds16(A + (size_t)(m0 + r) * K + k0 + c, &As[buf][0][0] + seg * 512);
      gload_lds16(Bt + (size_t)(n0 + r) * K + k0 + c, &Bs[buf][0][0] + seg * 512);
    }
  };

  stage(0, 0);
  __syncthreads();
  int nk = K >> 5;
  int cur = 0;
  for (int t = 0; t < nk; ++t) {
    if (t + 1 < nk) stage(cur ^ 1, (t + 1) << 5);
    bf16x8 am[4], bn[4];
#pragma unroll
    for (int mf = 0; mf < 4; ++mf)
      am[mf] = *reinterpret_cast<const bf16x8*>(&As[cur][wr * 64 + mf * 16 + lr][lh * 8]);
#pragma unroll
    for (int nf = 0; nf < 4; ++nf)
      bn[nf] = *reinterpret_cast<const bf16x8*>(&Bs[cur][wc * 64 + nf * 16 + lr][lh * 8]);
#pragma unroll
    for (int mf = 0; mf < 4; ++mf)
#pragma unroll
      for (int nf = 0; nf < 4; ++nf)
        acc[mf][nf] = mfma16(am[mf], bn[nf], acc[mf][nf]);
    __syncthreads();
    cur ^= 1;
  }

#pragma unroll
  for (int nf = 0; nf < 4; ++nf) {
    int col = n0 + wc * 64 + nf * 16 + lr;
    float b = bias ? bias[col] : 0.f;
#pragma unroll
    for (int mf = 0; mf < 4; ++mf) {
      int row0 = m0 + wr * 64 + mf * 16 + lh * 4;
#pragma unroll
      for (int j = 0; j < 4; ++j)
        C[(size_t)(row0 + j) * N + col] = acc[mf][nf][j] + b;
    }
  }
}

// ---------------- RoPE + layout ----------------
__global__ __launch_bounds__(256) void rope_kernel(const float* __restrict__ QKV,
                                                   bf16* __restrict__ Qb,
                                                   bf16* __restrict__ Kb,
                                                   bf16* __restrict__ Vt) {
  int t = blockIdx.x;
  int b = t >> 11, s = t & (S_LEN - 1);
  const float* row = QKV + (size_t)t * NQKV;
  int tid = threadIdx.x;
  __shared__ float cs[32], sn[32];
  if (tid < 32) {
    float inv = expf(-(float)tid * (13.815510557964274f / 32.0f));  // 1e6^(-d/32)
    float a = (float)s * inv;
    float c, si;
    sincosf(a, &si, &c);
    cs[tid] = c; sn[tid] = si;
  }
  __syncthreads();
  for (int p = tid; p < NHEADS * 32; p += 256) {
    int h = p >> 5, d = p & 31;
    float v1 = row[h * 64 + d], v2 = row[h * 64 + d + 32];
    float c = cs[d], si = sn[d];
    size_t base = ((size_t)(b * NHEADS + h) * S_LEN + s) * HDIM;
    Qb[base + d]      = (bf16)((v1 * c - v2 * si) * 0.125f);
    Qb[base + d + 32] = (bf16)((v2 * c + v1 * si) * 0.125f);
  }
  if (tid < NKVH * 32) {
    int kh = tid >> 5, d = tid & 31;
    float v1 = row[896 + kh * 64 + d], v2 = row[896 + kh * 64 + d + 32];
    float c = cs[d], si = sn[d];
    size_t base = ((size_t)(b * NKVH + kh) * S_LEN + s) * HDIM;
    Kb[base + d]      = (bf16)(v1 * c - v2 * si);
    Kb[base + d + 32] = (bf16)(v2 * c + v1 * si);
  }
  if (tid < NKVH * 64) {
    int kh = tid >> 6, d = tid & 63;
    float v = row[1024 + tid];
    Vt[((size_t)(b * NKVH + kh) * HDIM + d) * S_LEN + s] = (bf16)v;
  }
}

// ---------------- flash attention, split-KV partials ----------------
// Opart: [28][80][64][64] bf16 (unnormalized), Oml: [28][80][64][2] f32 (m, l)
__global__ __launch_bounds__(256) void attn_kernel(const bf16* __restrict__ Qb,
                                                   const bf16* __restrict__ Kb,
                                                   const bf16* __restrict__ Vt,
                                                   bf16* __restrict__ Opart,
                                                   float* __restrict__ Oml) {
  int blk = blockIdx.x;
  int c = blk % NCHUNK, bh = blk / NCHUNK;
  int qt, ch;
  chunk_map(c, qt, ch);
  int h = bh % NHEADS, b = bh / NHEADS;
  int q0 = qt * 64;
  int kv = h / 7;
  int kc0 = ch * 512;
  int kend = min(kc0 + 512, q0 + 64);
  int tid = threadIdx.x, wid = tid >> 6, lane = tid & 63;
  int lr = lane & 15, lh = lane >> 4;

  const bf16* Qp = Qb + ((size_t)(b * NHEADS + h) * S_LEN + q0 + wid * 16) * HDIM;
  const bf16* Kp = Kb + ((size_t)(b * NKVH + kv) * S_LEN) * HDIM;
  const bf16* Vp = Vt + ((size_t)(b * NKVH + kv) * HDIM) * S_LEN;

  bf16x8 aq[2];
#pragma unroll
  for (int kk = 0; kk < 2; ++kk)
    aq[kk] = *reinterpret_cast<const bf16x8*>(Qp + (size_t)lr * HDIM + kk * 32 + lh * 8);

  float m[4], l[4];
  f32x4 o[4] = {};
#pragma unroll
  for (int j = 0; j < 4; ++j) { m[j] = -__builtin_inff(); l[j] = 0.f; }

  __shared__ __align__(16) bf16 Plds[4][16][72];

  int rowg = q0 + wid * 16 + lh * 4;
  for (int kv0 = kc0; kv0 < kend; kv0 += 64) {
    bool diag = (kv0 == q0);
    f32x4 sacc[4] = {};
#pragma unroll
    for (int nf = 0; nf < 4; ++nf) {
#pragma unroll
      for (int kk = 0; kk < 2; ++kk) {
        bf16x8 bk = *reinterpret_cast<const bf16x8*>(
            Kp + (size_t)(kv0 + nf * 16 + lr) * HDIM + kk * 32 + lh * 8);
        sacc[nf] = mfma16(aq[kk], bk, sacc[nf]);
      }
    }
    float p[4][4], mloc[4];
#pragma unroll
    for (int j = 0; j < 4; ++j) mloc[j] = -__builtin_inff();
#pragma unroll
    for (int nf = 0; nf < 4; ++nf) {
      int colg = kv0 + nf * 16 + lr;
#pragma unroll
      for (int j = 0; j < 4; ++j) {
        float x = sacc[nf][j];
        if (diag && colg > rowg + j) x = -__builtin_inff();
        p[nf][j] = x;
        mloc[j] = fmaxf(mloc[j], x);
      }
    }
#pragma unroll
    for (int mask = 1; mask < 16; mask <<= 1)
#pragma unroll
      for (int j = 0; j < 4; ++j)
        mloc[j] = fmaxf(mloc[j], __shfl_xor(mloc[j], mask));
    float alpha[4], rs[4];
#pragma unroll
    for (int j = 0; j < 4; ++j) {
      float mn = fmaxf(m[j], mloc[j]);
      alpha[j] = __expf(m[j] - mn);
      m[j] = mn;
      rs[j] = 0.f;
    }
#pragma unroll
    for (int nf = 0; nf < 4; ++nf)
#pragma unroll
      for (int j = 0; j < 4; ++j) {
        float e = __expf(p[nf][j] - m[j]);
        p[nf][j] = e;
        rs[j] += e;
      }
#pragma unroll
    for (int mask = 1; mask < 16; mask <<= 1)
#pragma unroll
      for (int j = 0; j < 4; ++j)
        rs[j] += __shfl_xor(rs[j], mask);
#pragma unroll
    for (int j = 0; j < 4; ++j)
      l[j] = l[j] * alpha[j] + rs[j];
#pragma unroll
    for (int nf = 0; nf < 4; ++nf)
#pragma unroll
      for (int j = 0; j < 4; ++j)
        o[nf][j] *= alpha[j];
#pragma unroll
    for (int nf = 0; nf < 4; ++nf)
#pragma unroll
      for (int j = 0; j < 4; ++j)
        Plds[wid][lh * 4 + j][nf * 16 + lr] = (bf16)p[nf][j];
    bf16x8 pa[2];
#pragma unroll
    for (int kk = 0; kk < 2; ++kk)
      pa[kk] = *reinterpret_cast<const bf16x8*>(&Plds[wid][lr][kk * 32 + lh * 8]);
#pragma unroll
    for (int nf = 0; nf < 4; ++nf) {
#pragma unroll
      for (int kk = 0; kk < 2; ++kk) {
        bf16x8 bv = *reinterpret_cast<const bf16x8*>(
            Vp + (size_t)(nf * 16 + lr) * S_LEN + kv0 + kk * 32 + lh * 8);
        o[nf] = mfma16(pa[kk], bv, o[nf]);
      }
    }
  }
  // epilogue: write unnormalized partial O (bf16) + per-row (m, l)
  size_t pbase = ((size_t)bh * NCHUNK + c) * 4096;
#pragma unroll
  for (int nf = 0; nf < 4; ++nf) {
    int col = nf * 16 + lr;
#pragma unroll
    for (int j = 0; j < 4; ++j) {
      int rloc = wid * 16 + lh * 4 + j;
      Opart[pbase + (size_t)rloc * 64 + col] = (bf16)o[nf][j];
    }
  }
  if (lr == 0) {
    size_t mbase = ((size_t)bh * NCHUNK + c) * 64;
#pragma unroll
    for (int j = 0; j < 4; ++j) {
      int rloc = wid * 16 + lh * 4 + j;
      Oml[(mbase + rloc) * 2]     = m[j];
      Oml[(mbase + rloc) * 2 + 1] = l[j];
    }
  }
}

// ---------------- combine partials ----------------
__global__ __launch_bounds__(256) void combine_kernel(const bf16* __restrict__ Opart,
                                                      const float* __restrict__ Oml,
                                                      bf16* __restrict__ Ob) {
  int blk = blockIdx.x;            // bh*32 + qt
  int qt = blk & 31, bh = blk >> 5;
  int h = bh % NHEADS, b = bh / NHEADS;
  int nch = (qt >> 3) + 1;
  int coff = chunk_off(qt);
  int t = threadIdx.x;
  int row = t >> 2, cg = t & 3;    // 16 cols per thread

  float mi[4], li[4], M = -__builtin_inff();
  for (int i = 0; i < nch; ++i) {
    size_t mb = (((size_t)bh * NCHUNK + coff + i) * 64 + row) * 2;
    mi[i] = Oml[mb]; li[i] = Oml[mb + 1];
    M = fmaxf(M, mi[i]);
  }
  float L = 0.f, w[4];
  for (int i = 0; i < nch; ++i) { w[i] = __expf(mi[i] - M); L += w[i] * li[i]; }
  float acc[16];
#pragma unroll
  for (int k = 0; k < 16; ++k) acc[k] = 0.f;
  for (int i = 0; i < nch; ++i) {
    const bf16* src = Opart + (((size_t)bh * NCHUNK + coff + i) * 64 + row) * 64 + cg * 16;
    bf16x8 v0 = *reinterpret_cast<const bf16x8*>(src);
    bf16x8 v1 = *reinterpret_cast<const bf16x8*>(src + 8);
#pragma unroll
    for (int k = 0; k < 8; ++k) { acc[k] += w[i] * (float)v0[k]; acc[8 + k] += w[i] * (float)v1[k]; }
  }
  float inv = 1.0f / L;
  bf16x8 r0, r1;
#pragma unroll
  for (int k = 0; k < 8; ++k) { r0[k] = (bf16)(acc[k] * inv); r1[k] = (bf16)(acc[8 + k] * inv); }
  bf16* dst = Ob + ((size_t)(b * S_LEN) + qt * 64 + row) * HID + h * 64 + cg * 16;
  *reinterpret_cast<bf16x8*>(dst) = r0;
  *reinterpret_cast<bf16x8*>(dst + 8) = r1;
}

// ---------------- launch ----------------
extern "C" void kernel_launch(void* const* d_in, const int* in_sizes, int n_in,
                              void* d_out, int out_size, void* d_ws, size_t ws_size,
                              hipStream_t stream) {
  (void)in_sizes; (void)n_in; (void)out_size; (void)ws_size;
  const float* X  = (const float*)d_in[0];
  const float* Wq = (const float*)d_in[2];
  const float* bq = (const float*)d_in[3];
  const float* Wk = (const float*)d_in[4];
  const float* bk = (const float*)d_in[5];
  const float* Wv = (const float*)d_in[6];
  const float* bv = (const float*)d_in[7];
  const float* Wo = (const float*)d_in[8];
  float* OUT = (float*)d_out;

  char* ws = (char*)d_ws;
  bf16*  Xb    = (bf16*)(ws);                 // 4096*896*2  = 7,340,032
  bf16*  WqkvT = (bf16*)(ws + 7340032);       // 1152*896*2  = 2,064,384
  bf16*  WoT   = (bf16*)(ws + 9404416);       // 896*896*2   = 1,605,632
  float* biasq = (float*)(ws + 11010048);     // 1152*4
  float* QKV   = (float*)(ws + 11014656);     // 4096*1152*4 = 18,874,368
  bf16*  Qbuf  = (bf16*)(ws + 29889024);      // 4096*896*2
  bf16*  Kbuf  = (bf16*)(ws + 37229056);      // 2*2*2048*64*2
  bf16*  Vbuf  = (bf16*)(ws + 38277632);      // 2*2*64*2048*2  (ends 39,326,208)
  // attention-phase reuse of dead regions:
  bf16*  Opart = (bf16*)(ws + 11014656);      // 28*80*64*64*2 = 18,350,080 (in dead QKV)
  float* Oml   = (float*)(ws + 7340032);      // 28*80*64*2*4  = 1,146,880  (in dead WqkvT)
  bf16*  Obuf  = Xb;                          // reuse (Xb dead after GEMM1)

  cast_x_kernel<<<3584, 256, 0, stream>>>(X, Xb, 917504);
  transpose_cast_kernel<<<dim3(28, 28), 256, 0, stream>>>(Wq, WqkvT, 896);
  transpose_cast_kernel<<<dim3(4, 28), 256, 0, stream>>>(Wk, WqkvT + (size_t)896 * 896, 128);
  transpose_cast_kernel<<<dim3(4, 28), 256, 0, stream>>>(Wv, WqkvT + (size_t)1024 * 896, 128);
  transpose_cast_kernel<<<dim3(28, 28), 256, 0, stream>>>(Wo, WoT, 896);
  pack_bias_kernel<<<5, 256, 0, stream>>>(bq, bk, bv, biasq);

  gemm_bt_kernel<<<dim3(9, 32), 256, 0, stream>>>(Xb, WqkvT, biasq, QKV, 4096, 1152, 896);
  rope_kernel<<<4096, 256, 0, stream>>>(QKV, Qbuf, Kbuf, Vbuf);
  attn_kernel<<<28 * NCHUNK, 256, 0, stream>>>(Qbuf, Kbuf, Vbuf, Opart, Oml);
  combine_kernel<<<896, 256, 0, stream>>>(Opart, Oml, Obuf);
  gemm_bt_kernel<<<dim3(7, 32), 256, 0, stream>>>(Obuf, WoT, nullptr, OUT, 4096, 896, 896);
}

// Round 3
// 185.696 us; speedup vs baseline: 1.6456x; 1.2453x over previous
//
#include <hip/hip_runtime.h>

#define S_LEN 2048
#define NHEADS 14
#define NKVH 2
#define HDIM 64
#define HID 896
#define NQKV 1152
#define NCHUNK 40   // per bh: sum over 16 q-blocks(128 rows) of ceil(128*(qt+1)/512)

typedef __bf16 bf16;
typedef __bf16 bf16x4 __attribute__((ext_vector_type(4)));
typedef __bf16 bf16x8 __attribute__((ext_vector_type(8)));
typedef float f32x4 __attribute__((ext_vector_type(4)));

__device__ inline f32x4 mfma16(bf16x8 a, bf16x8 b, f32x4 c) {
  return __builtin_amdgcn_mfma_f32_16x16x32_bf16(a, b, c, 0, 0, 0);
}

__device__ inline void gload_lds16(const bf16* g, bf16* l) {
  __builtin_amdgcn_global_load_lds(
      (const __attribute__((address_space(1))) void*)g,
      (__attribute__((address_space(3))) void*)l, 16, 0, 0);
}

// chunk index c (0..39) -> (q-block qt 0..15, chunk-within ch); nch(qt)=(qt>>2)+1
__device__ inline void chunk_map(int c, int& qt, int& ch) {
  if (c < 4)       { qt = c;                ch = 0; }
  else if (c < 12) { qt = 4 + ((c - 4) >> 1); ch = (c - 4) & 1; }
  else if (c < 24) { int d = c - 12; qt = 8 + d / 3; ch = d % 3; }
  else             { int d = c - 24; qt = 12 + (d >> 2); ch = d & 3; }
}

// ---------------- cast / pack kernels ----------------
__global__ __launch_bounds__(256) void cast_x_kernel(const float* __restrict__ X,
                                                     bf16* __restrict__ Xb, int n4) {
  int i = blockIdx.x * 256 + threadIdx.x;
  if (i >= n4) return;
  float4 v = reinterpret_cast<const float4*>(X)[i];
  bf16x4 o;
  o[0] = (bf16)v.x; o[1] = (bf16)v.y; o[2] = (bf16)v.z; o[3] = (bf16)v.w;
  reinterpret_cast<bf16x4*>(Xb)[i] = o;
}

// W: [896][N] f32 row-major  ->  WT: [N][896] bf16 row-major
__global__ __launch_bounds__(256) void transpose_cast_kernel(const float* __restrict__ W,
                                                             bf16* __restrict__ WT, int N) {
  __shared__ float tile[32][33];
  int n0 = blockIdx.x * 32, k0 = blockIdx.y * 32;
  int tx = threadIdx.x & 31, ty = threadIdx.x >> 5;  // 32 x 8
#pragma unroll
  for (int j = 0; j < 32; j += 8)
    tile[ty + j][tx] = W[(size_t)(k0 + ty + j) * N + n0 + tx];
  __syncthreads();
#pragma unroll
  for (int j = 0; j < 32; j += 8)
    WT[(size_t)(n0 + ty + j) * HID + k0 + tx] = (bf16)tile[tx][ty + j];
}

__global__ __launch_bounds__(256) void pack_bias_kernel(const float* __restrict__ bq,
                                                        const float* __restrict__ bk,
                                                        const float* __restrict__ bv,
                                                        float* __restrict__ out) {
  int i = blockIdx.x * 256 + threadIdx.x;
  if (i < 896) out[i] = bq[i];
  else if (i < 1024) out[i] = bk[i - 896];
  else if (i < 1152) out[i] = bv[i - 1024];
}

// ---------------- GEMM: C[M][N] = A[M][K](bf16) * Bt[N][K](bf16)^T + bias ----------------
__global__ __launch_bounds__(256) void gemm_bt_kernel(const bf16* __restrict__ A,
                                                      const bf16* __restrict__ Bt,
                                                      const float* __restrict__ bias,
                                                      float* __restrict__ C,
                                                      int M, int N, int K) {
  __shared__ __align__(16) bf16 As[2][128][32];
  __shared__ __align__(16) bf16 Bs[2][128][32];
  int n0 = blockIdx.x * 128, m0 = blockIdx.y * 128;
  int tid = threadIdx.x;
  int wid = tid >> 6, lane = tid & 63;
  int lr = lane & 15, lh = lane >> 4;
  int wr = wid >> 1, wc = wid & 1;
  f32x4 acc[4][4] = {};

  auto stage = [&](int buf, int k0) {
#pragma unroll
    for (int i = 0; i < 2; ++i) {
      int seg = i * 4 + wid;              // 0..7, wave-uniform
      int idx = seg * 512 + lane * 8;     // element index within 128x32 tile
      int r = idx >> 5, c = idx & 31;
      gload_lds16(A + (size_t)(m0 + r) * K + k0 + c, &As[buf][0][0] + seg * 512);
      gload_lds16(Bt + (size_t)(n0 + r) * K + k0 + c, &Bs[buf][0][0] + seg * 512);
    }
  };

  stage(0, 0);
  __syncthreads();
  int nk = K >> 5;
  int cur = 0;
  for (int t = 0; t < nk; ++t) {
    if (t + 1 < nk) stage(cur ^ 1, (t + 1) << 5);
    bf16x8 am[4], bn[4];
#pragma unroll
    for (int mf = 0; mf < 4; ++mf)
      am[mf] = *reinterpret_cast<const bf16x8*>(&As[cur][wr * 64 + mf * 16 + lr][lh * 8]);
#pragma unroll
    for (int nf = 0; nf < 4; ++nf)
      bn[nf] = *reinterpret_cast<const bf16x8*>(&Bs[cur][wc * 64 + nf * 16 + lr][lh * 8]);
#pragma unroll
    for (int mf = 0; mf < 4; ++mf)
#pragma unroll
      for (int nf = 0; nf < 4; ++nf)
        acc[mf][nf] = mfma16(am[mf], bn[nf], acc[mf][nf]);
    __syncthreads();
    cur ^= 1;
  }

#pragma unroll
  for (int nf = 0; nf < 4; ++nf) {
    int col = n0 + wc * 64 + nf * 16 + lr;
    float b = bias ? bias[col] : 0.f;
#pragma unroll
    for (int mf = 0; mf < 4; ++mf) {
      int row0 = m0 + wr * 64 + mf * 16 + lh * 4;
#pragma unroll
      for (int j = 0; j < 4; ++j)
        C[(size_t)(row0 + j) * N + col] = acc[mf][nf][j] + b;
    }
  }
}

// ---------------- RoPE + layout ----------------
__global__ __launch_bounds__(256) void rope_kernel(const float* __restrict__ QKV,
                                                   bf16* __restrict__ Qb,
                                                   bf16* __restrict__ Kb,
                                                   bf16* __restrict__ Vt) {
  int t = blockIdx.x;
  int b = t >> 11, s = t & (S_LEN - 1);
  const float* row = QKV + (size_t)t * NQKV;
  int tid = threadIdx.x;
  __shared__ float cs[32], sn[32];
  if (tid < 32) {
    float inv = expf(-(float)tid * (13.815510557964274f / 32.0f));  // 1e6^(-d/32)
    float a = (float)s * inv;
    float c, si;
    sincosf(a, &si, &c);
    cs[tid] = c; sn[tid] = si;
  }
  __syncthreads();
  for (int p = tid; p < NHEADS * 32; p += 256) {
    int h = p >> 5, d = p & 31;
    float v1 = row[h * 64 + d], v2 = row[h * 64 + d + 32];
    float c = cs[d], si = sn[d];
    size_t base = ((size_t)(b * NHEADS + h) * S_LEN + s) * HDIM;
    Qb[base + d]      = (bf16)((v1 * c - v2 * si) * 0.125f);
    Qb[base + d + 32] = (bf16)((v2 * c + v1 * si) * 0.125f);
  }
  if (tid < NKVH * 32) {
    int kh = tid >> 5, d = tid & 31;
    float v1 = row[896 + kh * 64 + d], v2 = row[896 + kh * 64 + d + 32];
    float c = cs[d], si = sn[d];
    size_t base = ((size_t)(b * NKVH + kh) * S_LEN + s) * HDIM;
    Kb[base + d]      = (bf16)(v1 * c - v2 * si);
    Kb[base + d + 32] = (bf16)(v2 * c + v1 * si);
  }
  if (tid < NKVH * 64) {
    int kh = tid >> 6, d = tid & 63;
    float v = row[1024 + tid];
    Vt[((size_t)(b * NKVH + kh) * HDIM + d) * S_LEN + s] = (bf16)v;
  }
}

// ---------------- flash attention, split-KV partials, 32 q-rows/wave ----------------
// Opart: [28][40][128][64] bf16 (unnormalized), Oml: [28][40][128][2] f32 (m, l)
__global__ __launch_bounds__(256) void attn_kernel(const bf16* __restrict__ Qb,
                                                   const bf16* __restrict__ Kb,
                                                   const bf16* __restrict__ Vt,
                                                   bf16* __restrict__ Opart,
                                                   float* __restrict__ Oml) {
  int blk = blockIdx.x;
  int c = blk % NCHUNK, bh = blk / NCHUNK;
  int qt, ch;
  chunk_map(c, qt, ch);
  int h = bh % NHEADS, b = bh / NHEADS;
  int q0 = qt * 128;
  int kv = h / 7;
  int kc0 = ch * 512;
  int kend = min(kc0 + 512, q0 + 128);
  int tid = threadIdx.x, wid = tid >> 6, lane = tid & 63;
  int lr = lane & 15, lh = lane >> 4;

  const bf16* Qp = Qb + ((size_t)(b * NHEADS + h) * S_LEN + q0 + wid * 32) * HDIM;
  const bf16* Kp = Kb + ((size_t)(b * NKVH + kv) * S_LEN) * HDIM;
  const bf16* Vp = Vt + ((size_t)(b * NKVH + kv) * HDIM) * S_LEN;

  bf16x8 aq[2][2];
#pragma unroll
  for (int f = 0; f < 2; ++f)
#pragma unroll
    for (int kk = 0; kk < 2; ++kk)
      aq[f][kk] = *reinterpret_cast<const bf16x8*>(
          Qp + (size_t)(f * 16 + lr) * HDIM + kk * 32 + lh * 8);

  float m[2][4], l[2][4];
  f32x4 o[2][4] = {};
#pragma unroll
  for (int f = 0; f < 2; ++f)
#pragma unroll
    for (int j = 0; j < 4; ++j) { m[f][j] = -__builtin_inff(); l[f][j] = 0.f; }

  __shared__ __align__(16) bf16 Plds[4][32][72];

  auto kload = [&](bf16x8 (&kb)[8], int kv0) {
#pragma unroll
    for (int nf = 0; nf < 4; ++nf)
#pragma unroll
      for (int kk = 0; kk < 2; ++kk)
        kb[nf * 2 + kk] = *reinterpret_cast<const bf16x8*>(
            Kp + (size_t)(kv0 + nf * 16 + lr) * HDIM + kk * 32 + lh * 8);
  };

  auto step = [&](bf16x8 (&kb)[8], bf16x8 (&kbn)[8], int kv0, bool last) {
    f32x4 sacc[2][4] = {};
#pragma unroll
    for (int f = 0; f < 2; ++f)
#pragma unroll
      for (int nf = 0; nf < 4; ++nf)
#pragma unroll
        for (int kk = 0; kk < 2; ++kk)
          sacc[f][nf] = mfma16(aq[f][kk], kb[nf * 2 + kk], sacc[f][nf]);
    // issue V loads early (hidden under softmax)
    bf16x8 vb[8];
#pragma unroll
    for (int nf = 0; nf < 4; ++nf)
#pragma unroll
      for (int kk = 0; kk < 2; ++kk)
        vb[nf * 2 + kk] = *reinterpret_cast<const bf16x8*>(
            Vp + (size_t)(nf * 16 + lr) * S_LEN + kv0 + kk * 32 + lh * 8);
    // prefetch next K tile
    if (!last) kload(kbn, kv0 + 64);

#pragma unroll
    for (int f = 0; f < 2; ++f) {
      int rbase = q0 + wid * 32 + f * 16 + lh * 4;  // + j -> global q row
      bool needMask = (kv0 + 63 > q0 + wid * 32 + f * 16);
      float p[4][4], mloc[4];
#pragma unroll
      for (int j = 0; j < 4; ++j) mloc[j] = -__builtin_inff();
#pragma unroll
      for (int nf = 0; nf < 4; ++nf) {
        int colg = kv0 + nf * 16 + lr;
#pragma unroll
        for (int j = 0; j < 4; ++j) {
          float x = sacc[f][nf][j];
          if (needMask && colg > rbase + j) x = -__builtin_inff();
          p[nf][j] = x;
          mloc[j] = fmaxf(mloc[j], x);
        }
      }
#pragma unroll
      for (int mask = 1; mask < 16; mask <<= 1)
#pragma unroll
        for (int j = 0; j < 4; ++j)
          mloc[j] = fmaxf(mloc[j], __shfl_xor(mloc[j], mask));
      float alpha[4], rs[4];
#pragma unroll
      for (int j = 0; j < 4; ++j) {
        float mn = fmaxf(m[f][j], mloc[j]);
        alpha[j] = __expf(m[f][j] - mn);
        m[f][j] = mn;
        rs[j] = 0.f;
      }
#pragma unroll
      for (int nf = 0; nf < 4; ++nf)
#pragma unroll
        for (int j = 0; j < 4; ++j) {
          float e = __expf(p[nf][j] - m[f][j]);
          p[nf][j] = e;
          rs[j] += e;
        }
#pragma unroll
      for (int mask = 1; mask < 16; mask <<= 1)
#pragma unroll
        for (int j = 0; j < 4; ++j)
          rs[j] += __shfl_xor(rs[j], mask);
#pragma unroll
      for (int j = 0; j < 4; ++j)
        l[f][j] = l[f][j] * alpha[j] + rs[j];
#pragma unroll
      for (int nf = 0; nf < 4; ++nf)
#pragma unroll
        for (int j = 0; j < 4; ++j)
          o[f][nf][j] *= alpha[j];
#pragma unroll
      for (int nf = 0; nf < 4; ++nf)
#pragma unroll
        for (int j = 0; j < 4; ++j)
          Plds[wid][f * 16 + lh * 4 + j][nf * 16 + lr] = (bf16)p[nf][j];
    }
    // PV
#pragma unroll
    for (int f = 0; f < 2; ++f) {
      bf16x8 pa[2];
#pragma unroll
      for (int kk = 0; kk < 2; ++kk)
        pa[kk] = *reinterpret_cast<const bf16x8*>(&Plds[wid][f * 16 + lr][kk * 32 + lh * 8]);
#pragma unroll
      for (int nf = 0; nf < 4; ++nf)
#pragma unroll
        for (int kk = 0; kk < 2; ++kk)
          o[f][nf] = mfma16(pa[kk], vb[nf * 2 + kk], o[f][nf]);
    }
  };

  int nt = (kend - kc0) >> 6;
  bf16x8 kbA[8], kbB[8];
  kload(kbA, kc0);
  int t = 0;
  while (true) {
    bool last = (t + 1 >= nt);
    step(kbA, kbB, kc0 + (t << 6), last);
    if (last) break;
    ++t;
    last = (t + 1 >= nt);
    step(kbB, kbA, kc0 + (t << 6), last);
    if (last) break;
    ++t;
  }

  // epilogue: write unnormalized partial O (bf16) + per-row (m, l)
  size_t pbase = ((size_t)bh * NCHUNK + c) * (128 * 64);
#pragma unroll
  for (int f = 0; f < 2; ++f) {
#pragma unroll
    for (int nf = 0; nf < 4; ++nf) {
      int col = nf * 16 + lr;
#pragma unroll
      for (int j = 0; j < 4; ++j) {
        int rloc = wid * 32 + f * 16 + lh * 4 + j;
        Opart[pbase + (size_t)rloc * 64 + col] = (bf16)o[f][nf][j];
      }
    }
    if (lr == 0) {
      size_t mbase = ((size_t)bh * NCHUNK + c) * 128;
#pragma unroll
      for (int j = 0; j < 4; ++j) {
        int rloc = wid * 32 + f * 16 + lh * 4 + j;
        Oml[(mbase + rloc) * 2]     = m[f][j];
        Oml[(mbase + rloc) * 2 + 1] = l[f][j];
      }
    }
  }
}

// ---------------- combine partials ----------------
__global__ __launch_bounds__(256) void combine_kernel(const bf16* __restrict__ Opart,
                                                      const float* __restrict__ Oml,
                                                      bf16* __restrict__ Ob) {
  int blk = blockIdx.x;            // bh*16 + qt
  int qt = blk & 15, bh = blk >> 4;
  int h = bh % NHEADS, b = bh / NHEADS;
  int a = qt >> 2, bb = qt & 3;
  int nch = a + 1;
  int coff = (a + 1) * (2 * a + bb);
  int t = threadIdx.x;
  int row = t >> 1, cg = t & 1;    // 32 cols per thread

  float M = -__builtin_inff();
  for (int i = 0; i < nch; ++i)
    M = fmaxf(M, Oml[(((size_t)bh * NCHUNK + coff + i) * 128 + row) * 2]);
  float L = 0.f;
  for (int i = 0; i < nch; ++i) {
    size_t mb = (((size_t)bh * NCHUNK + coff + i) * 128 + row) * 2;
    L += __expf(Oml[mb] - M) * Oml[mb + 1];
  }
  float acc[32];
#pragma unroll
  for (int k = 0; k < 32; ++k) acc[k] = 0.f;
  for (int i = 0; i < nch; ++i) {
    size_t mb = (((size_t)bh * NCHUNK + coff + i) * 128 + row) * 2;
    float w = __expf(Oml[mb] - M);
    const bf16* src = Opart + (((size_t)bh * NCHUNK + coff + i) * 128 + row) * 64 + cg * 32;
#pragma unroll
    for (int v = 0; v < 4; ++v) {
      bf16x8 x = *reinterpret_cast<const bf16x8*>(src + v * 8);
#pragma unroll
      for (int k = 0; k < 8; ++k) acc[v * 8 + k] += w * (float)x[k];
    }
  }
  float inv = 1.0f / L;
  bf16* dst = Ob + ((size_t)(b * S_LEN) + qt * 128 + row) * HID + h * 64 + cg * 32;
#pragma unroll
  for (int v = 0; v < 4; ++v) {
    bf16x8 r;
#pragma unroll
    for (int k = 0; k < 8; ++k) r[k] = (bf16)(acc[v * 8 + k] * inv);
    *reinterpret_cast<bf16x8*>(dst + v * 8) = r;
  }
}

// ---------------- launch ----------------
extern "C" void kernel_launch(void* const* d_in, const int* in_sizes, int n_in,
                              void* d_out, int out_size, void* d_ws, size_t ws_size,
                              hipStream_t stream) {
  (void)in_sizes; (void)n_in; (void)out_size; (void)ws_size;
  const float* X  = (const float*)d_in[0];
  const float* Wq = (const float*)d_in[2];
  const float* bq = (const float*)d_in[3];
  const float* Wk = (const float*)d_in[4];
  const float* bk = (const float*)d_in[5];
  const float* Wv = (const float*)d_in[6];
  const float* bv = (const float*)d_in[7];
  const float* Wo = (const float*)d_in[8];
  float* OUT = (float*)d_out;

  char* ws = (char*)d_ws;
  bf16*  Xb    = (bf16*)(ws);                 // 4096*896*2  = 7,340,032
  bf16*  WqkvT = (bf16*)(ws + 7340032);       // 1152*896*2  = 2,064,384
  bf16*  WoT   = (bf16*)(ws + 9404416);       // 896*896*2   = 1,605,632
  float* biasq = (float*)(ws + 11010048);     // 1152*4
  float* QKV   = (float*)(ws + 11014656);     // 4096*1152*4 = 18,874,368
  bf16*  Qbuf  = (bf16*)(ws + 29889024);      // 4096*896*2
  bf16*  Kbuf  = (bf16*)(ws + 37229056);      // 2*2*2048*64*2
  bf16*  Vbuf  = (bf16*)(ws + 38277632);      // 2*2*64*2048*2  (ends 39,326,208)
  // attention-phase reuse of dead regions:
  bf16*  Opart = (bf16*)(ws + 11014656);      // 28*40*128*64*2 = 18,350,080 (in dead QKV)
  float* Oml   = (float*)(ws + 7340032);      // 28*40*128*2*4  = 1,146,880  (in dead WqkvT)
  bf16*  Obuf  = Xb;                          // reuse (Xb dead after GEMM1)

  cast_x_kernel<<<3584, 256, 0, stream>>>(X, Xb, 917504);
  transpose_cast_kernel<<<dim3(28, 28), 256, 0, stream>>>(Wq, WqkvT, 896);
  transpose_cast_kernel<<<dim3(4, 28), 256, 0, stream>>>(Wk, WqkvT + (size_t)896 * 896, 128);
  transpose_cast_kernel<<<dim3(4, 28), 256, 0, stream>>>(Wv, WqkvT + (size_t)1024 * 896, 128);
  transpose_cast_kernel<<<dim3(28, 28), 256, 0, stream>>>(Wo, WoT, 896);
  pack_bias_kernel<<<5, 256, 0, stream>>>(bq, bk, bv, biasq);

  gemm_bt_kernel<<<dim3(9, 32), 256, 0, stream>>>(Xb, WqkvT, biasq, QKV, 4096, 1152, 896);
  rope_kernel<<<4096, 256, 0, stream>>>(QKV, Qbuf, Kbuf, Vbuf);
  attn_kernel<<<28 * NCHUNK, 256, 0, stream>>>(Qbuf, Kbuf, Vbuf, Opart, Oml);
  combine_kernel<<<28 * 16, 256, 0, stream>>>(Opart, Oml, Obuf);
  gemm_bt_kernel<<<dim3(7, 32), 256, 0, stream>>>(Obuf, WoT, nullptr, OUT, 4096, 896, 896);
}

// Round 4
// 169.116 us; speedup vs baseline: 1.8070x; 1.0980x over previous
//
#include <hip/hip_runtime.h>

#define S_LEN 2048
#define NHEADS 14
#define NKVH 2
#define HDIM 64
#define HID 896
#define NQKV 1152
#define NCHUNK 40   // per bh: sum over 16 q-blocks(128 rows) of ceil(128*(qt+1)/512)

typedef __bf16 bf16;
typedef __bf16 bf16x4 __attribute__((ext_vector_type(4)));
typedef __bf16 bf16x8 __attribute__((ext_vector_type(8)));
typedef float f32x4 __attribute__((ext_vector_type(4)));

__device__ inline f32x4 mfma16(bf16x8 a, bf16x8 b, f32x4 c) {
  return __builtin_amdgcn_mfma_f32_16x16x32_bf16(a, b, c, 0, 0, 0);
}

__device__ inline void gload_lds16(const bf16* g, bf16* l) {
  __builtin_amdgcn_global_load_lds(
      (const __attribute__((address_space(1))) void*)g,
      (__attribute__((address_space(3))) void*)l, 16, 0, 0);
}
__device__ inline void gload_lds16b(const void* g, void* l) {
  __builtin_amdgcn_global_load_lds(
      (const __attribute__((address_space(1))) void*)g,
      (__attribute__((address_space(3))) void*)l, 16, 0, 0);
}

// chunk index c (0..39) -> (q-block qt 0..15, chunk-within ch); nch(qt)=(qt>>2)+1
__device__ inline void chunk_map(int c, int& qt, int& ch) {
  if (c < 4)       { qt = c;                ch = 0; }
  else if (c < 12) { qt = 4 + ((c - 4) >> 1); ch = (c - 4) & 1; }
  else if (c < 24) { int d = c - 12; qt = 8 + d / 3; ch = d % 3; }
  else             { int d = c - 24; qt = 12 + (d >> 2); ch = d & 3; }
}

// ---------------- cast / pack kernels ----------------
__global__ __launch_bounds__(256) void cast_x_kernel(const float* __restrict__ X,
                                                     bf16* __restrict__ Xb, int n4) {
  int i = blockIdx.x * 256 + threadIdx.x;
  if (i >= n4) return;
  float4 v = reinterpret_cast<const float4*>(X)[i];
  bf16x4 o;
  o[0] = (bf16)v.x; o[1] = (bf16)v.y; o[2] = (bf16)v.z; o[3] = (bf16)v.w;
  reinterpret_cast<bf16x4*>(Xb)[i] = o;
}

// W: [896][N] f32 row-major  ->  WT: [N][896] bf16 row-major
__global__ __launch_bounds__(256) void transpose_cast_kernel(const float* __restrict__ W,
                                                             bf16* __restrict__ WT, int N) {
  __shared__ float tile[32][33];
  int n0 = blockIdx.x * 32, k0 = blockIdx.y * 32;
  int tx = threadIdx.x & 31, ty = threadIdx.x >> 5;  // 32 x 8
#pragma unroll
  for (int j = 0; j < 32; j += 8)
    tile[ty + j][tx] = W[(size_t)(k0 + ty + j) * N + n0 + tx];
  __syncthreads();
#pragma unroll
  for (int j = 0; j < 32; j += 8)
    WT[(size_t)(n0 + ty + j) * HID + k0 + tx] = (bf16)tile[tx][ty + j];
}

__global__ __launch_bounds__(256) void pack_bias_kernel(const float* __restrict__ bq,
                                                        const float* __restrict__ bk,
                                                        const float* __restrict__ bv,
                                                        float* __restrict__ out) {
  int i = blockIdx.x * 256 + threadIdx.x;
  if (i < 896) out[i] = bq[i];
  else if (i < 1024) out[i] = bk[i - 896];
  else if (i < 1152) out[i] = bv[i - 1024];
}

// ---------------- GEMM: C[M][N] = A[M][K](bf16) * Bt[N][K](bf16)^T + bias ----------------
__global__ __launch_bounds__(256) void gemm_bt_kernel(const bf16* __restrict__ A,
                                                      const bf16* __restrict__ Bt,
                                                      const float* __restrict__ bias,
                                                      float* __restrict__ C,
                                                      int M, int N, int K) {
  __shared__ __align__(16) bf16 As[2][128][32];
  __shared__ __align__(16) bf16 Bs[2][128][32];
  int n0 = blockIdx.x * 128, m0 = blockIdx.y * 128;
  int tid = threadIdx.x;
  int wid = tid >> 6, lane = tid & 63;
  int lr = lane & 15, lh = lane >> 4;
  int wr = wid >> 1, wc = wid & 1;
  f32x4 acc[4][4] = {};

  auto stage = [&](int buf, int k0) {
#pragma unroll
    for (int i = 0; i < 2; ++i) {
      int seg = i * 4 + wid;              // 0..7, wave-uniform
      int idx = seg * 512 + lane * 8;     // element index within 128x32 tile
      int r = idx >> 5, c = idx & 31;
      gload_lds16(A + (size_t)(m0 + r) * K + k0 + c, &As[buf][0][0] + seg * 512);
      gload_lds16(Bt + (size_t)(n0 + r) * K + k0 + c, &Bs[buf][0][0] + seg * 512);
    }
  };

  stage(0, 0);
  __syncthreads();
  int nk = K >> 5;
  int cur = 0;
  for (int t = 0; t < nk; ++t) {
    if (t + 1 < nk) stage(cur ^ 1, (t + 1) << 5);
    bf16x8 am[4], bn[4];
#pragma unroll
    for (int mf = 0; mf < 4; ++mf)
      am[mf] = *reinterpret_cast<const bf16x8*>(&As[cur][wr * 64 + mf * 16 + lr][lh * 8]);
#pragma unroll
    for (int nf = 0; nf < 4; ++nf)
      bn[nf] = *reinterpret_cast<const bf16x8*>(&Bs[cur][wc * 64 + nf * 16 + lr][lh * 8]);
#pragma unroll
    for (int mf = 0; mf < 4; ++mf)
#pragma unroll
      for (int nf = 0; nf < 4; ++nf)
        acc[mf][nf] = mfma16(am[mf], bn[nf], acc[mf][nf]);
    __syncthreads();
    cur ^= 1;
  }

#pragma unroll
  for (int nf = 0; nf < 4; ++nf) {
    int col = n0 + wc * 64 + nf * 16 + lr;
    float b = bias ? bias[col] : 0.f;
#pragma unroll
    for (int mf = 0; mf < 4; ++mf) {
      int row0 = m0 + wr * 64 + mf * 16 + lh * 4;
#pragma unroll
      for (int j = 0; j < 4; ++j)
        C[(size_t)(row0 + j) * N + col] = acc[mf][nf][j] + b;
    }
  }
}

// ---------------- RoPE + layout ----------------
// Writes Qb [B][14][S][64] pre-scaled by 0.125*log2(e) (log2-domain softmax);
// Kb [B][2][S][64] with element d stored at d ^ ((s&7)<<3)  (LDS swizzle pre-applied);
// Vt [B][2][64][S] with column (s&63) stored at (s&63) ^ ((d&7)<<3).
__global__ __launch_bounds__(256) void rope_kernel(const float* __restrict__ QKV,
                                                   bf16* __restrict__ Qb,
                                                   bf16* __restrict__ Kb,
                                                   bf16* __restrict__ Vt) {
  int t = blockIdx.x;
  int b = t >> 11, s = t & (S_LEN - 1);
  const float* row = QKV + (size_t)t * NQKV;
  int tid = threadIdx.x;
  __shared__ float cs[32], sn[32];
  if (tid < 32) {
    float inv = expf(-(float)tid * (13.815510557964274f / 32.0f));  // 1e6^(-d/32)
    float a = (float)s * inv;
    float c, si;
    sincosf(a, &si, &c);
    cs[tid] = c; sn[tid] = si;
  }
  __syncthreads();
  const float QSCALE = 0.125f * 1.44269504088896f;  // 1/sqrt(64) * log2(e)
  for (int p = tid; p < NHEADS * 32; p += 256) {
    int h = p >> 5, d = p & 31;
    float v1 = row[h * 64 + d], v2 = row[h * 64 + d + 32];
    float c = cs[d], si = sn[d];
    size_t base = ((size_t)(b * NHEADS + h) * S_LEN + s) * HDIM;
    Qb[base + d]      = (bf16)((v1 * c - v2 * si) * QSCALE);
    Qb[base + d + 32] = (bf16)((v2 * c + v1 * si) * QSCALE);
  }
  if (tid < NKVH * 32) {
    int kh = tid >> 5, d = tid & 31;
    float v1 = row[896 + kh * 64 + d], v2 = row[896 + kh * 64 + d + 32];
    float c = cs[d], si = sn[d];
    size_t base = ((size_t)(b * NKVH + kh) * S_LEN + s) * HDIM;
    int sw = (s & 7) << 3;
    Kb[base + (d ^ sw)]        = (bf16)(v1 * c - v2 * si);
    Kb[base + ((d + 32) ^ sw)] = (bf16)(v2 * c + v1 * si);
  }
  if (tid < NKVH * 64) {
    int kh = tid >> 6, d = tid & 63;
    float v = row[1024 + tid];
    int col = (s & ~63) | ((s & 63) ^ ((d & 7) << 3));
    Vt[((size_t)(b * NKVH + kh) * HDIM + d) * S_LEN + col] = (bf16)v;
  }
}

// ---------------- flash attention, split-KV, LDS-staged K/V ----------------
// Opart: [28][40][128][64] bf16 (unnormalized), Oml: [28][40][128][2] f32 (m, l in log2 domain)
__global__ __launch_bounds__(256) void attn_kernel(const bf16* __restrict__ Qb,
                                                   const bf16* __restrict__ Kb,
                                                   const bf16* __restrict__ Vt,
                                                   bf16* __restrict__ Opart,
                                                   float* __restrict__ Oml) {
  int blk = blockIdx.x;
  int c = blk % NCHUNK, bh = blk / NCHUNK;
  int qt, ch;
  chunk_map(c, qt, ch);
  int h = bh % NHEADS, b = bh / NHEADS;
  int q0 = qt * 128;
  int kv = h / 7;
  int kc0 = ch * 512;
  int kend = min(kc0 + 512, q0 + 128);
  int nt = (kend - kc0) >> 6;
  int tid = threadIdx.x, wid = tid >> 6, lane = tid & 63;
  int lr = lane & 15, lh = lane >> 4;
  int swk = (lr & 7) << 4;   // byte XOR for swizzled K/V LDS reads

  const bf16* Qp = Qb + ((size_t)(b * NHEADS + h) * S_LEN + q0 + wid * 32) * HDIM;
  const char* KpB = (const char*)(Kb + (size_t)(b * NKVH + kv) * S_LEN * HDIM);
  const char* VpB = (const char*)(Vt + (size_t)(b * NKVH + kv) * HDIM * S_LEN);

  __shared__ __align__(16) bf16 Ks[2][4096];
  __shared__ __align__(16) bf16 Vs[2][4096];
  __shared__ __align__(16) bf16 Plds[4][32][72];

  bf16x8 aq[2][2];
#pragma unroll
  for (int f = 0; f < 2; ++f)
#pragma unroll
    for (int kk = 0; kk < 2; ++kk)
      aq[f][kk] = *reinterpret_cast<const bf16x8*>(
          Qp + (size_t)(f * 16 + lr) * HDIM + kk * 32 + lh * 8);

  float m[2][4], l[2][4];
  f32x4 o[2][4] = {};
#pragma unroll
  for (int f = 0; f < 2; ++f)
#pragma unroll
    for (int j = 0; j < 4; ++j) { m[f][j] = -__builtin_inff(); l[f][j] = 0.f; }

  // cooperative stage of one 64-kv tile of K and V (wave w stages rows [w*16,w*16+16))
  auto stage = [&](int buf, int kv0) {
#pragma unroll
    for (int i = 0; i < 2; ++i) {
      gload_lds16b(KpB + (size_t)kv0 * 128 + wid * 2048 + i * 1024 + lane * 16,
                   &Ks[buf][wid * 1024 + i * 512]);
      int d = wid * 16 + i * 8 + (lane >> 3);
      gload_lds16b(VpB + (size_t)d * (S_LEN * 2) + kv0 * 2 + (lane & 7) * 16,
                   &Vs[buf][wid * 1024 + i * 512]);
    }
  };

  stage(0, kc0);
  __syncthreads();

  int cur = 0;
  for (int t = 0; t < nt; ++t) {
    int kv0 = kc0 + (t << 6);
    // ---- QK^T from LDS (K fragments shared across both f) ----
    f32x4 sacc[2][4] = {};
    const char* KsB = (const char*)&Ks[cur][0];
#pragma unroll
    for (int nf = 0; nf < 4; ++nf)
#pragma unroll
      for (int kk = 0; kk < 2; ++kk) {
        bf16x8 kb = *(const bf16x8*)(KsB + (nf * 16 + lr) * 128 + ((kk * 64 + lh * 16) ^ swk));
        sacc[0][nf] = mfma16(aq[0][kk], kb, sacc[0][nf]);
        sacc[1][nf] = mfma16(aq[1][kk], kb, sacc[1][nf]);
      }
    // issue next-tile staging early (drains at the end-of-iteration barrier)
    if (t + 1 < nt) stage(cur ^ 1, kv0 + 64);

    // ---- mask + row max ----
    float mloc[2][4];
#pragma unroll
    for (int f = 0; f < 2; ++f) {
      int rstart = q0 + wid * 32 + f * 16;
      int rbase = rstart + lh * 4;
      bool needMask = (kv0 + 63 > rstart);
#pragma unroll
      for (int j = 0; j < 4; ++j) mloc[f][j] = -__builtin_inff();
#pragma unroll
      for (int nf = 0; nf < 4; ++nf) {
        int colg = kv0 + nf * 16 + lr;
#pragma unroll
        for (int j = 0; j < 4; ++j) {
          float x = sacc[f][nf][j];
          if (needMask && colg > rbase + j) x = -__builtin_inff();
          sacc[f][nf][j] = x;
          mloc[f][j] = fmaxf(mloc[f][j], x);
        }
      }
#pragma unroll
      for (int mask = 1; mask < 16; mask <<= 1)
#pragma unroll
        for (int j = 0; j < 4; ++j)
          mloc[f][j] = fmaxf(mloc[f][j], __shfl_xor(mloc[f][j], mask));
    }
    // ---- defer-max: rescale only if some row grew by > 8 (log2 units) ----
    float g = mloc[0][0] - m[0][0];
#pragma unroll
    for (int j = 1; j < 4; ++j) g = fmaxf(g, mloc[0][j] - m[0][j]);
#pragma unroll
    for (int j = 0; j < 4; ++j) g = fmaxf(g, mloc[1][j] - m[1][j]);
    if (!__all(g <= 8.0f)) {
#pragma unroll
      for (int f = 0; f < 2; ++f)
#pragma unroll
        for (int j = 0; j < 4; ++j) {
          float mn = fmaxf(m[f][j], mloc[f][j]);
          float alpha = exp2f(m[f][j] - mn);
          m[f][j] = mn;
          l[f][j] *= alpha;
#pragma unroll
          for (int nf = 0; nf < 4; ++nf) o[f][nf][j] *= alpha;
        }
    }
    // ---- exp2 + row-sum + P -> LDS ----
#pragma unroll
    for (int f = 0; f < 2; ++f) {
      float rs[4] = {0.f, 0.f, 0.f, 0.f};
#pragma unroll
      for (int nf = 0; nf < 4; ++nf)
#pragma unroll
        for (int j = 0; j < 4; ++j) {
          float e = exp2f(sacc[f][nf][j] - m[f][j]);
          sacc[f][nf][j] = e;
          rs[j] += e;
        }
#pragma unroll
      for (int mask = 1; mask < 16; mask <<= 1)
#pragma unroll
        for (int j = 0; j < 4; ++j)
          rs[j] += __shfl_xor(rs[j], mask);
#pragma unroll
      for (int j = 0; j < 4; ++j) l[f][j] += rs[j];
#pragma unroll
      for (int nf = 0; nf < 4; ++nf)
#pragma unroll
        for (int j = 0; j < 4; ++j)
          Plds[wid][f * 16 + lh * 4 + j][nf * 16 + lr] = (bf16)sacc[f][nf][j];
    }
    // ---- PV from LDS ----
    const char* VsB = (const char*)&Vs[cur][0];
    bf16x8 vb[8];
#pragma unroll
    for (int nf = 0; nf < 4; ++nf)
#pragma unroll
      for (int kk = 0; kk < 2; ++kk)
        vb[nf * 2 + kk] = *(const bf16x8*)(VsB + (nf * 16 + lr) * 128 + ((kk * 64 + lh * 16) ^ swk));
#pragma unroll
    for (int f = 0; f < 2; ++f) {
      bf16x8 pa[2];
#pragma unroll
      for (int kk = 0; kk < 2; ++kk)
        pa[kk] = *reinterpret_cast<const bf16x8*>(&Plds[wid][f * 16 + lr][kk * 32 + lh * 8]);
#pragma unroll
      for (int nf = 0; nf < 4; ++nf)
#pragma unroll
        for (int kk = 0; kk < 2; ++kk)
          o[f][nf] = mfma16(pa[kk], vb[nf * 2 + kk], o[f][nf]);
    }
    __syncthreads();   // drains staging vmcnt + protects buffer flip
    cur ^= 1;
  }

  // epilogue: write unnormalized partial O (bf16) + per-row (m, l)
  size_t pbase = ((size_t)bh * NCHUNK + c) * (128 * 64);
#pragma unroll
  for (int f = 0; f < 2; ++f) {
#pragma unroll
    for (int nf = 0; nf < 4; ++nf) {
      int col = nf * 16 + lr;
#pragma unroll
      for (int j = 0; j < 4; ++j) {
        int rloc = wid * 32 + f * 16 + lh * 4 + j;
        Opart[pbase + (size_t)rloc * 64 + col] = (bf16)o[f][nf][j];
      }
    }
    if (lr == 0) {
      size_t mbase = ((size_t)bh * NCHUNK + c) * 128;
#pragma unroll
      for (int j = 0; j < 4; ++j) {
        int rloc = wid * 32 + f * 16 + lh * 4 + j;
        Oml[(mbase + rloc) * 2]     = m[f][j];
        Oml[(mbase + rloc) * 2 + 1] = l[f][j];
      }
    }
  }
}

// ---------------- combine partials (m in log2 domain -> exp2f) ----------------
__global__ __launch_bounds__(256) void combine_kernel(const bf16* __restrict__ Opart,
                                                      const float* __restrict__ Oml,
                                                      bf16* __restrict__ Ob) {
  int blk = blockIdx.x;            // bh*16 + qt
  int qt = blk & 15, bh = blk >> 4;
  int h = bh % NHEADS, b = bh / NHEADS;
  int a = qt >> 2, bb = qt & 3;
  int nch = a + 1;
  int coff = (a + 1) * (2 * a + bb);
  int t = threadIdx.x;
  int row = t >> 1, cg = t & 1;    // 32 cols per thread

  float M = -__builtin_inff();
  for (int i = 0; i < nch; ++i)
    M = fmaxf(M, Oml[(((size_t)bh * NCHUNK + coff + i) * 128 + row) * 2]);
  float L = 0.f;
  for (int i = 0; i < nch; ++i) {
    size_t mb = (((size_t)bh * NCHUNK + coff + i) * 128 + row) * 2;
    L += exp2f(Oml[mb] - M) * Oml[mb + 1];
  }
  float acc[32];
#pragma unroll
  for (int k = 0; k < 32; ++k) acc[k] = 0.f;
  for (int i = 0; i < nch; ++i) {
    size_t mb = (((size_t)bh * NCHUNK + coff + i) * 128 + row) * 2;
    float w = exp2f(Oml[mb] - M);
    const bf16* src = Opart + (((size_t)bh * NCHUNK + coff + i) * 128 + row) * 64 + cg * 32;
#pragma unroll
    for (int v = 0; v < 4; ++v) {
      bf16x8 x = *reinterpret_cast<const bf16x8*>(src + v * 8);
#pragma unroll
      for (int k = 0; k < 8; ++k) acc[v * 8 + k] += w * (float)x[k];
    }
  }
  float inv = 1.0f / L;
  bf16* dst = Ob + ((size_t)(b * S_LEN) + qt * 128 + row) * HID + h * 64 + cg * 32;
#pragma unroll
  for (int v = 0; v < 4; ++v) {
    bf16x8 r;
#pragma unroll
    for (int k = 0; k < 8; ++k) r[k] = (bf16)(acc[v * 8 + k] * inv);
    *reinterpret_cast<bf16x8*>(dst + v * 8) = r;
  }
}

// ---------------- launch ----------------
extern "C" void kernel_launch(void* const* d_in, const int* in_sizes, int n_in,
                              void* d_out, int out_size, void* d_ws, size_t ws_size,
                              hipStream_t stream) {
  (void)in_sizes; (void)n_in; (void)out_size; (void)ws_size;
  const float* X  = (const float*)d_in[0];
  const float* Wq = (const float*)d_in[2];
  const float* bq = (const float*)d_in[3];
  const float* Wk = (const float*)d_in[4];
  const float* bk = (const float*)d_in[5];
  const float* Wv = (const float*)d_in[6];
  const float* bv = (const float*)d_in[7];
  const float* Wo = (const float*)d_in[8];
  float* OUT = (float*)d_out;

  char* ws = (char*)d_ws;
  bf16*  Xb    = (bf16*)(ws);                 // 4096*896*2  = 7,340,032
  bf16*  WqkvT = (bf16*)(ws + 7340032);       // 1152*896*2  = 2,064,384
  bf16*  WoT   = (bf16*)(ws + 9404416);       // 896*896*2   = 1,605,632
  float* biasq = (float*)(ws + 11010048);     // 1152*4
  float* QKV   = (float*)(ws + 11014656);     // 4096*1152*4 = 18,874,368
  bf16*  Qbuf  = (bf16*)(ws + 29889024);      // 4096*896*2
  bf16*  Kbuf  = (bf16*)(ws + 37229056);      // 2*2*2048*64*2
  bf16*  Vbuf  = (bf16*)(ws + 38277632);      // 2*2*64*2048*2  (ends 39,326,208)
  // attention-phase reuse of dead regions:
  bf16*  Opart = (bf16*)(ws + 11014656);      // 28*40*128*64*2 = 18,350,080 (in dead QKV)
  float* Oml   = (float*)(ws + 7340032);      // 28*40*128*2*4  = 1,146,880  (in dead WqkvT)
  bf16*  Obuf  = Xb;                          // reuse (Xb dead after GEMM1)

  cast_x_kernel<<<3584, 256, 0, stream>>>(X, Xb, 917504);
  transpose_cast_kernel<<<dim3(28, 28), 256, 0, stream>>>(Wq, WqkvT, 896);
  transpose_cast_kernel<<<dim3(4, 28), 256, 0, stream>>>(Wk, WqkvT + (size_t)896 * 896, 128);
  transpose_cast_kernel<<<dim3(4, 28), 256, 0, stream>>>(Wv, WqkvT + (size_t)1024 * 896, 128);
  transpose_cast_kernel<<<dim3(28, 28), 256, 0, stream>>>(Wo, WoT, 896);
  pack_bias_kernel<<<5, 256, 0, stream>>>(bq, bk, bv, biasq);

  gemm_bt_kernel<<<dim3(9, 32), 256, 0, stream>>>(Xb, WqkvT, biasq, QKV, 4096, 1152, 896);
  rope_kernel<<<4096, 256, 0, stream>>>(QKV, Qbuf, Kbuf, Vbuf);
  attn_kernel<<<28 * NCHUNK, 256, 0, stream>>>(Qbuf, Kbuf, Vbuf, Opart, Oml);
  combine_kernel<<<28 * 16, 256, 0, stream>>>(Opart, Oml, Obuf);
  gemm_bt_kernel<<<dim3(7, 32), 256, 0, stream>>>(Obuf, WoT, nullptr, OUT, 4096, 896, 896);
}

// Round 5
// 121.675 us; speedup vs baseline: 2.5115x; 1.3899x over previous
//
#include <hip/hip_runtime.h>

#define S_LEN 2048
#define NHEADS 14
#define NKVH 2
#define HDIM 64
#define HID 896
#define NQKV 1152
#define NCHUNK 40   // per bh: sum over 16 q-blocks(128 rows) of ceil(128*(qt+1)/512)

typedef __bf16 bf16;
typedef __bf16 bf16x4 __attribute__((ext_vector_type(4)));
typedef __bf16 bf16x8 __attribute__((ext_vector_type(8)));
typedef float f32x4 __attribute__((ext_vector_type(4)));
typedef unsigned int u32x4 __attribute__((ext_vector_type(4)));

__device__ inline f32x4 mfma16(bf16x8 a, bf16x8 b, f32x4 c) {
  return __builtin_amdgcn_mfma_f32_16x16x32_bf16(a, b, c, 0, 0, 0);
}

__device__ inline void gload_lds16(const bf16* g, bf16* l) {
  __builtin_amdgcn_global_load_lds(
      (const __attribute__((address_space(1))) void*)g,
      (__attribute__((address_space(3))) void*)l, 16, 0, 0);
}
__device__ inline void gload_lds16b(const void* g, void* l) {
  __builtin_amdgcn_global_load_lds(
      (const __attribute__((address_space(1))) void*)g,
      (__attribute__((address_space(3))) void*)l, 16, 0, 0);
}

__device__ inline unsigned cvtpk(float lo, float hi) {
  unsigned r;
  asm("v_cvt_pk_bf16_f32 %0, %1, %2" : "=v"(r) : "v"(lo), "v"(hi));
  return r;
}

// chunk index c (0..39) -> (q-block qt 0..15, chunk-within ch); nch(qt)=(qt>>2)+1
__device__ inline void chunk_map(int c, int& qt, int& ch) {
  if (c < 4)       { qt = c;                ch = 0; }
  else if (c < 12) { qt = 4 + ((c - 4) >> 1); ch = (c - 4) & 1; }
  else if (c < 24) { int d = c - 12; qt = 8 + d / 3; ch = d % 3; }
  else             { int d = c - 24; qt = 12 + (d >> 2); ch = d & 3; }
}

// ---------------- fused prep: cast X, transpose-cast all W, pack bias ----------------
__global__ __launch_bounds__(256) void prep_kernel(
    const float* __restrict__ X, bf16* __restrict__ Xb,
    const float* __restrict__ Wq, const float* __restrict__ Wk,
    const float* __restrict__ Wv, const float* __restrict__ Wo,
    bf16* __restrict__ WqkvT, bf16* __restrict__ WoT,
    const float* __restrict__ bq, const float* __restrict__ bk,
    const float* __restrict__ bv, float* __restrict__ biasq) {
  __shared__ float tile[32][33];
  int blk = blockIdx.x;
  int tid = threadIdx.x;
  if (blk < 3584) {
    int i = blk * 256 + tid;
    if (i < 917504) {
      float4 v = reinterpret_cast<const float4*>(X)[i];
      bf16x4 o;
      o[0] = (bf16)v.x; o[1] = (bf16)v.y; o[2] = (bf16)v.z; o[3] = (bf16)v.w;
      reinterpret_cast<bf16x4*>(Xb)[i] = o;
    }
    return;
  }
  if (blk < 5376) {
    int t = blk - 3584;
    const float* W; bf16* dst; int N, bx, by;
    if (t < 784)       { W = Wq; dst = WqkvT;                      N = 896; bx = t % 28;          by = t / 28; }
    else if (t < 896)  { int u = t - 784;  W = Wk; dst = WqkvT + (size_t)896 * 896;  N = 128; bx = u % 4; by = u / 4; }
    else if (t < 1008) { int u = t - 896;  W = Wv; dst = WqkvT + (size_t)1024 * 896; N = 128; bx = u % 4; by = u / 4; }
    else               { int u = t - 1008; W = Wo; dst = WoT;      N = 896; bx = u % 28;          by = u / 28; }
    int n0 = bx * 32, k0 = by * 32;
    int tx = tid & 31, ty = tid >> 5;  // 32 x 8
#pragma unroll
    for (int j = 0; j < 32; j += 8)
      tile[ty + j][tx] = W[(size_t)(k0 + ty + j) * N + n0 + tx];
    __syncthreads();
#pragma unroll
    for (int j = 0; j < 32; j += 8)
      dst[(size_t)(n0 + ty + j) * HID + k0 + tx] = (bf16)tile[tx][ty + j];
    return;
  }
  int i = (blk - 5376) * 256 + tid;
  if (i < 896) biasq[i] = bq[i];
  else if (i < 1024) biasq[i] = bk[i - 896];
  else if (i < 1152) biasq[i] = bv[i - 1024];
}

// ---------------- GEMM: C[M][N] = A[M][K](bf16) * Bt[N][K](bf16)^T + bias ----------------
__global__ __launch_bounds__(256) void gemm_bt_kernel(const bf16* __restrict__ A,
                                                      const bf16* __restrict__ Bt,
                                                      const float* __restrict__ bias,
                                                      float* __restrict__ C,
                                                      int M, int N, int K) {
  __shared__ __align__(16) bf16 As[2][128][32];
  __shared__ __align__(16) bf16 Bs[2][128][32];
  int n0 = blockIdx.x * 128, m0 = blockIdx.y * 128;
  int tid = threadIdx.x;
  int wid = tid >> 6, lane = tid & 63;
  int lr = lane & 15, lh = lane >> 4;
  int wr = wid >> 1, wc = wid & 1;
  f32x4 acc[4][4] = {};

  auto stage = [&](int buf, int k0) {
#pragma unroll
    for (int i = 0; i < 2; ++i) {
      int seg = i * 4 + wid;              // 0..7, wave-uniform
      int idx = seg * 512 + lane * 8;     // element index within 128x32 tile
      int r = idx >> 5, c = idx & 31;
      gload_lds16(A + (size_t)(m0 + r) * K + k0 + c, &As[buf][0][0] + seg * 512);
      gload_lds16(Bt + (size_t)(n0 + r) * K + k0 + c, &Bs[buf][0][0] + seg * 512);
    }
  };

  stage(0, 0);
  __syncthreads();
  int nk = K >> 5;
  int cur = 0;
  for (int t = 0; t < nk; ++t) {
    if (t + 1 < nk) stage(cur ^ 1, (t + 1) << 5);
    bf16x8 am[4], bn[4];
#pragma unroll
    for (int mf = 0; mf < 4; ++mf)
      am[mf] = *reinterpret_cast<const bf16x8*>(&As[cur][wr * 64 + mf * 16 + lr][lh * 8]);
#pragma unroll
    for (int nf = 0; nf < 4; ++nf)
      bn[nf] = *reinterpret_cast<const bf16x8*>(&Bs[cur][wc * 64 + nf * 16 + lr][lh * 8]);
#pragma unroll
    for (int mf = 0; mf < 4; ++mf)
#pragma unroll
      for (int nf = 0; nf < 4; ++nf)
        acc[mf][nf] = mfma16(am[mf], bn[nf], acc[mf][nf]);
    __syncthreads();
    cur ^= 1;
  }

#pragma unroll
  for (int nf = 0; nf < 4; ++nf) {
    int col = n0 + wc * 64 + nf * 16 + lr;
    float b = bias ? bias[col] : 0.f;
#pragma unroll
    for (int mf = 0; mf < 4; ++mf) {
      int row0 = m0 + wr * 64 + mf * 16 + lh * 4;
#pragma unroll
      for (int j = 0; j < 4; ++j)
        C[(size_t)(row0 + j) * N + col] = acc[mf][nf][j] + b;
    }
  }
}

// ---------------- RoPE + layout ----------------
// Qb [B][14][S][64] pre-scaled by 0.125*log2(e);
// Kb [B][2][S][64], element d stored at d ^ (((s&7)^((s>>3)&1))<<3);
// Vt [B][2][64][S], column (s&63) stored at (s&63) ^ ((d&7)<<3).
__global__ __launch_bounds__(256) void rope_kernel(const float* __restrict__ QKV,
                                                   bf16* __restrict__ Qb,
                                                   bf16* __restrict__ Kb,
                                                   bf16* __restrict__ Vt) {
  int t = blockIdx.x;
  int b = t >> 11, s = t & (S_LEN - 1);
  const float* row = QKV + (size_t)t * NQKV;
  int tid = threadIdx.x;
  __shared__ float cs[32], sn[32];
  if (tid < 32) {
    float inv = expf(-(float)tid * (13.815510557964274f / 32.0f));  // 1e6^(-d/32)
    float a = (float)s * inv;
    float c, si;
    sincosf(a, &si, &c);
    cs[tid] = c; sn[tid] = si;
  }
  __syncthreads();
  const float QSCALE = 0.125f * 1.44269504088896f;  // 1/sqrt(64) * log2(e)
  for (int p = tid; p < NHEADS * 32; p += 256) {
    int h = p >> 5, d = p & 31;
    float v1 = row[h * 64 + d], v2 = row[h * 64 + d + 32];
    float c = cs[d], si = sn[d];
    size_t base = ((size_t)(b * NHEADS + h) * S_LEN + s) * HDIM;
    Qb[base + d]      = (bf16)((v1 * c - v2 * si) * QSCALE);
    Qb[base + d + 32] = (bf16)((v2 * c + v1 * si) * QSCALE);
  }
  if (tid < NKVH * 32) {
    int kh = tid >> 5, d = tid & 31;
    float v1 = row[896 + kh * 64 + d], v2 = row[896 + kh * 64 + d + 32];
    float c = cs[d], si = sn[d];
    size_t base = ((size_t)(b * NKVH + kh) * S_LEN + s) * HDIM;
    int sw = (((s & 7) ^ ((s >> 3) & 1)) << 3);
    Kb[base + (d ^ sw)]        = (bf16)(v1 * c - v2 * si);
    Kb[base + ((d + 32) ^ sw)] = (bf16)(v2 * c + v1 * si);
  }
  if (tid < NKVH * 64) {
    int kh = tid >> 6, d = tid & 63;
    float v = row[1024 + tid];
    int col = (s & ~63) | ((s & 63) ^ ((d & 7) << 3));
    Vt[((size_t)(b * NKVH + kh) * HDIM + d) * S_LEN + col] = (bf16)v;
  }
}

// ---------------- flash attention: swapped QK^T, lane-local softmax ----------------
// Opart: [28][40][128][64] bf16 (unnormalized), Oml: [28][40][128][2] f32 (m, l in log2 domain)
__global__ __launch_bounds__(256, 4) void attn_kernel(const bf16* __restrict__ Qb,
                                                      const bf16* __restrict__ Kb,
                                                      const bf16* __restrict__ Vt,
                                                      bf16* __restrict__ Opart,
                                                      float* __restrict__ Oml) {
  int blk = blockIdx.x;
  int c = blk % NCHUNK, bh = blk / NCHUNK;
  int qt, ch;
  chunk_map(c, qt, ch);
  int h = bh % NHEADS, b = bh / NHEADS;
  int q0 = qt * 128;
  int kv = h / 7;
  int kc0 = ch * 512;
  int kend = min(kc0 + 512, q0 + 128);
  int nt = (kend - kc0) >> 6;
  int tid = threadIdx.x, wid = tid >> 6, lane = tid & 63;
  int lr = lane & 15, lh = lane >> 4;
  int swk = (lr & 7) << 4;   // byte XOR for V LDS reads

  const bf16* Qp = Qb + ((size_t)(b * NHEADS + h) * S_LEN + q0 + wid * 32) * HDIM;
  const char* KpB = (const char*)(Kb + (size_t)(b * NKVH + kv) * S_LEN * HDIM);
  const char* VpB = (const char*)(Vt + (size_t)(b * NKVH + kv) * HDIM * S_LEN);

  __shared__ __align__(16) bf16 Ks[2][4096];
  __shared__ __align__(16) bf16 Vs[2][4096];

  bf16x8 aq[2][2];
#pragma unroll
  for (int f = 0; f < 2; ++f)
#pragma unroll
    for (int kk = 0; kk < 2; ++kk)
      aq[f][kk] = *reinterpret_cast<const bf16x8*>(
          Qp + (size_t)(f * 16 + lr) * HDIM + kk * 32 + lh * 8);

  float m[2] = {-3.0e38f, -3.0e38f}, l[2] = {0.f, 0.f};
  f32x4 o[2][4] = {};

  auto stage = [&](int buf, int kv0) {
#pragma unroll
    for (int i = 0; i < 2; ++i) {
      gload_lds16b(KpB + (size_t)kv0 * 128 + wid * 2048 + i * 1024 + lane * 16,
                   &Ks[buf][wid * 1024 + i * 512]);
      int d = wid * 16 + i * 8 + (lane >> 3);
      gload_lds16b(VpB + (size_t)d * (S_LEN * 2) + kv0 * 2 + (lane & 7) * 16,
                   &Vs[buf][wid * 1024 + i * 512]);
    }
  };

  stage(0, kc0);
  __syncthreads();

  int qf0 = q0 + wid * 32;
  int cur = 0;
  for (int t = 0; t < nt; ++t) {
    int kv0 = kc0 + (t << 6);
    // ---- swapped QK^T: sacc[f][nf][j] = S[q = qf0+f*16+lr][k = kv0+g(nf, lh*4+j)] ----
    const char* KsB = (const char*)&Ks[cur][0];
    f32x4 sacc[2][4] = {};
#pragma unroll
    for (int nf = 0; nf < 4; ++nf) {
      int rowk = 8 * (lr >> 2) + (lr & 3) + ((nf & 1) << 2) + ((nf >> 1) << 5);
      int rsw = (((rowk & 7) ^ ((rowk >> 3) & 1)) << 4);
#pragma unroll
      for (int kk = 0; kk < 2; ++kk) {
        bf16x8 kb = *(const bf16x8*)(KsB + rowk * 128 + ((kk * 64 + lh * 16) ^ rsw));
        sacc[0][nf] = mfma16(kb, aq[0][kk], sacc[0][nf]);
        sacc[1][nf] = mfma16(kb, aq[1][kk], sacc[1][nf]);
      }
    }
    if (t + 1 < nt) stage(cur ^ 1, kv0 + 64);

    // ---- mask (wave-uniform skip) + lane-local row max ----
    float mx[2];
#pragma unroll
    for (int f = 0; f < 2; ++f) {
      int qg = qf0 + f * 16 + lr;
      if (kv0 + 63 > qf0 + f * 16) {
#pragma unroll
        for (int nf = 0; nf < 4; ++nf) {
          int kb0 = kv0 + ((nf & 1) << 2) + ((nf >> 1) << 5) + (lh << 3);
#pragma unroll
          for (int j = 0; j < 4; ++j)
            if (kb0 + j > qg) sacc[f][nf][j] = -3.0e38f;
        }
      }
      f32x4 m4 = sacc[f][0];
#pragma unroll
      for (int nf = 1; nf < 4; ++nf)
#pragma unroll
        for (int j = 0; j < 4; ++j) m4[j] = fmaxf(m4[j], sacc[f][nf][j]);
      float mxl = fmaxf(fmaxf(m4[0], m4[1]), fmaxf(m4[2], m4[3]));
      mxl = fmaxf(mxl, __shfl_xor(mxl, 16));
      mxl = fmaxf(mxl, __shfl_xor(mxl, 32));
      mx[f] = mxl;
    }
    // ---- defer-max rescale (rare) ----
    float g = fmaxf(mx[0] - m[0], mx[1] - m[1]);
    if (!__all(g <= 8.0f)) {
#pragma unroll
      for (int f = 0; f < 2; ++f) {
        float mn = fmaxf(m[f], mx[f]);
        float al = exp2f(m[f] - mn);
        m[f] = mn;
        l[f] *= al;
        f32x4 av;
#pragma unroll
        for (int j = 0; j < 4; ++j) av[j] = __shfl(al, (lh << 2) + j);
#pragma unroll
        for (int nf = 0; nf < 4; ++nf) o[f][nf] *= av;
      }
    }
    // ---- exp2 + lane-local sum + in-register P pack (zero LDS, zero shuffles) ----
    bf16x8 pa[2][2];
#pragma unroll
    for (int f = 0; f < 2; ++f) {
      f32x4 rs4 = {0.f, 0.f, 0.f, 0.f};
#pragma unroll
      for (int nf = 0; nf < 4; ++nf) {
#pragma unroll
        for (int j = 0; j < 4; ++j)
          sacc[f][nf][j] = exp2f(sacc[f][nf][j] - m[f]);
        rs4 += sacc[f][nf];
      }
      float rsum = (rs4[0] + rs4[1]) + (rs4[2] + rs4[3]);
      rsum += __shfl_xor(rsum, 16);
      rsum += __shfl_xor(rsum, 32);
      l[f] += rsum;
#pragma unroll
      for (int kk = 0; kk < 2; ++kk) {
        u32x4 w;
        w[0] = cvtpk(sacc[f][2 * kk][0], sacc[f][2 * kk][1]);
        w[1] = cvtpk(sacc[f][2 * kk][2], sacc[f][2 * kk][3]);
        w[2] = cvtpk(sacc[f][2 * kk + 1][0], sacc[f][2 * kk + 1][1]);
        w[3] = cvtpk(sacc[f][2 * kk + 1][2], sacc[f][2 * kk + 1][3]);
        pa[f][kk] = __builtin_bit_cast(bf16x8, w);
      }
    }
    // ---- PV ----
    const char* VsB = (const char*)&Vs[cur][0];
#pragma unroll
    for (int nf = 0; nf < 4; ++nf) {
#pragma unroll
      for (int kk = 0; kk < 2; ++kk) {
        bf16x8 vb = *(const bf16x8*)(VsB + (nf * 16 + lr) * 128 + ((kk * 64 + lh * 16) ^ swk));
        o[0][nf] = mfma16(pa[0][kk], vb, o[0][nf]);
        o[1][nf] = mfma16(pa[1][kk], vb, o[1][nf]);
      }
    }
    __syncthreads();   // drains staging vmcnt + protects buffer flip
    cur ^= 1;
  }

  // epilogue: write unnormalized partial O (bf16) + per-row (m, l)
  size_t pbase = ((size_t)bh * NCHUNK + c) * (128 * 64);
#pragma unroll
  for (int f = 0; f < 2; ++f)
#pragma unroll
    for (int nf = 0; nf < 4; ++nf) {
      int col = nf * 16 + lr;
#pragma unroll
      for (int j = 0; j < 4; ++j) {
        int rloc = wid * 32 + f * 16 + (lh << 2) + j;
        Opart[pbase + (size_t)rloc * 64 + col] = (bf16)o[f][nf][j];
      }
    }
  if (lane < 16) {
    size_t mbase = ((size_t)bh * NCHUNK + c) * 128;
#pragma unroll
    for (int f = 0; f < 2; ++f) {
      int rloc = wid * 32 + f * 16 + lane;
      Oml[(mbase + rloc) * 2]     = m[f];
      Oml[(mbase + rloc) * 2 + 1] = l[f];
    }
  }
}

// ---------------- combine partials (m in log2 domain -> exp2f) ----------------
__global__ __launch_bounds__(256) void combine_kernel(const bf16* __restrict__ Opart,
                                                      const float* __restrict__ Oml,
                                                      bf16* __restrict__ Ob) {
  int blk = blockIdx.x;            // bh*16 + qt
  int qt = blk & 15, bh = blk >> 4;
  int h = bh % NHEADS, b = bh / NHEADS;
  int a = qt >> 2, bb = qt & 3;
  int nch = a + 1;
  int coff = (a + 1) * (2 * a + bb);
  int t = threadIdx.x;
  int row = t >> 1, cg = t & 1;    // 32 cols per thread

  float M = -__builtin_inff();
  for (int i = 0; i < nch; ++i)
    M = fmaxf(M, Oml[(((size_t)bh * NCHUNK + coff + i) * 128 + row) * 2]);
  float L = 0.f;
  for (int i = 0; i < nch; ++i) {
    size_t mb = (((size_t)bh * NCHUNK + coff + i) * 128 + row) * 2;
    L += exp2f(Oml[mb] - M) * Oml[mb + 1];
  }
  float acc[32];
#pragma unroll
  for (int k = 0; k < 32; ++k) acc[k] = 0.f;
  for (int i = 0; i < nch; ++i) {
    size_t mb = (((size_t)bh * NCHUNK + coff + i) * 128 + row) * 2;
    float w = exp2f(Oml[mb] - M);
    const bf16* src = Opart + (((size_t)bh * NCHUNK + coff + i) * 128 + row) * 64 + cg * 32;
#pragma unroll
    for (int v = 0; v < 4; ++v) {
      bf16x8 x = *reinterpret_cast<const bf16x8*>(src + v * 8);
#pragma unroll
      for (int k = 0; k < 8; ++k) acc[v * 8 + k] += w * (float)x[k];
    }
  }
  float inv = 1.0f / L;
  bf16* dst = Ob + ((size_t)(b * S_LEN) + qt * 128 + row) * HID + h * 64 + cg * 32;
#pragma unroll
  for (int v = 0; v < 4; ++v) {
    bf16x8 r;
#pragma unroll
    for (int k = 0; k < 8; ++k) r[k] = (bf16)(acc[v * 8 + k] * inv);
    *reinterpret_cast<bf16x8*>(dst + v * 8) = r;
  }
}

// ---------------- launch ----------------
extern "C" void kernel_launch(void* const* d_in, const int* in_sizes, int n_in,
                              void* d_out, int out_size, void* d_ws, size_t ws_size,
                              hipStream_t stream) {
  (void)in_sizes; (void)n_in; (void)out_size; (void)ws_size;
  const float* X  = (const float*)d_in[0];
  const float* Wq = (const float*)d_in[2];
  const float* bq = (const float*)d_in[3];
  const float* Wk = (const float*)d_in[4];
  const float* bk = (const float*)d_in[5];
  const float* Wv = (const float*)d_in[6];
  const float* bv = (const float*)d_in[7];
  const float* Wo = (const float*)d_in[8];
  float* OUT = (float*)d_out;

  char* ws = (char*)d_ws;
  bf16*  Xb    = (bf16*)(ws);                 // 4096*896*2  = 7,340,032
  bf16*  WqkvT = (bf16*)(ws + 7340032);       // 1152*896*2  = 2,064,384
  bf16*  WoT   = (bf16*)(ws + 9404416);       // 896*896*2   = 1,605,632
  float* biasq = (float*)(ws + 11010048);     // 1152*4
  float* QKV   = (float*)(ws + 11014656);     // 4096*1152*4 = 18,874,368
  bf16*  Qbuf  = (bf16*)(ws + 29889024);      // 4096*896*2
  bf16*  Kbuf  = (bf16*)(ws + 37229056);      // 2*2*2048*64*2
  bf16*  Vbuf  = (bf16*)(ws + 38277632);      // 2*2*64*2048*2  (ends 39,326,208)
  // attention-phase reuse of dead regions:
  bf16*  Opart = (bf16*)(ws + 11014656);      // 28*40*128*64*2 = 18,350,080 (in dead QKV)
  float* Oml   = (float*)(ws + 7340032);      // 28*40*128*2*4  = 1,146,880  (in dead WqkvT)
  bf16*  Obuf  = Xb;                          // reuse (Xb dead after GEMM1)

  prep_kernel<<<5381, 256, 0, stream>>>(X, Xb, Wq, Wk, Wv, Wo, WqkvT, WoT,
                                        bq, bk, bv, biasq);
  gemm_bt_kernel<<<dim3(9, 32), 256, 0, stream>>>(Xb, WqkvT, biasq, QKV, 4096, 1152, 896);
  rope_kernel<<<4096, 256, 0, stream>>>(QKV, Qbuf, Kbuf, Vbuf);
  attn_kernel<<<28 * NCHUNK, 256, 0, stream>>>(Qbuf, Kbuf, Vbuf, Opart, Oml);
  combine_kernel<<<28 * 16, 256, 0, stream>>>(Opart, Oml, Obuf);
  gemm_bt_kernel<<<dim3(7, 32), 256, 0, stream>>>(Obuf, WoT, nullptr, OUT, 4096, 896, 896);
}